// Round 5
// baseline (1062.206 us; speedup 1.0000x reference)
//
#include <hip/hip_runtime.h>
#include <stdint.h>

#define T_SEQ 2048
#define DMODEL 2048
#define NH 16
#define NKV 8
#define DHEAD 128
#define DFF 8192

typedef float f32x4 __attribute__((ext_vector_type(4)));
typedef float f32x2 __attribute__((ext_vector_type(2)));
typedef __bf16 bf16x8 __attribute__((ext_vector_type(8)));
typedef unsigned short ushort_t;

typedef __attribute__((address_space(1))) void gvoid;
typedef __attribute__((address_space(3))) void lvoid;

__device__ inline unsigned short f2bf(float f) {
  unsigned int u = __float_as_uint(f);
  u += 0x7fffu + ((u >> 16) & 1u);
  return (unsigned short)(u >> 16);
}
__device__ inline float bf2f(unsigned short h) {
  return __uint_as_float(((unsigned int)h) << 16);
}

__device__ inline void gload_lds16(const void* g, void* l) {
  // 16B per lane; LDS dest is wave-uniform base + lane*16 (HW rule)
  __builtin_amdgcn_global_load_lds((gvoid*)g, (lvoid*)l, 16, 0, 0);
}

// ---------------------------------------------------------------------------
// Transpose + convert: in f32/bf16 [R][C] -> out bf16 [C][R].  Tile 64x64.
// ---------------------------------------------------------------------------
template <typename TIN>
__global__ __launch_bounds__(256) void k_transpose_bf16(const TIN* __restrict__ in,
                                                        ushort_t* __restrict__ out,
                                                        int R, int C) {
  __shared__ float tile[64 * 72];
  int tid = threadIdx.x;
  int r0 = blockIdx.y * 64, c0 = blockIdx.x * 64;
  int rl = tid >> 4;   // 0..15
  int cc = tid & 15;   // 16B col chunk
#pragma unroll
  for (int i = 0; i < 4; ++i) {
    int row = rl + i * 16;
    const TIN* src = in + (size_t)(r0 + row) * C + c0 + cc * 4;
    float v0, v1, v2, v3;
    if constexpr (sizeof(TIN) == 4) {
      f32x4 v = *(const f32x4*)src;
      v0 = v.x; v1 = v.y; v2 = v.z; v3 = v.w;
    } else {
      ushort4 v = *(const ushort4*)src;
      v0 = bf2f(v.x); v1 = bf2f(v.y); v2 = bf2f(v.z); v3 = bf2f(v.w);
    }
    int chunk = cc ^ (row & 15);
    f32x4 t = {v0, v1, v2, v3};
    *(f32x4*)&tile[row * 72 + chunk * 4] = t;
  }
  __syncthreads();
#pragma unroll
  for (int i = 0; i < 4; ++i) {
    int nrow = rl + i * 16;   // output row local = input col
    int k4 = cc * 4;          // output col local base = input row
    ushort4 o;
    {
      int k = k4 + 0;
      o.x = f2bf(tile[k * 72 + (((nrow >> 2) ^ (k & 15)) << 2) + (nrow & 3)]);
      k = k4 + 1;
      o.y = f2bf(tile[k * 72 + (((nrow >> 2) ^ (k & 15)) << 2) + (nrow & 3)]);
      k = k4 + 2;
      o.z = f2bf(tile[k * 72 + (((nrow >> 2) ^ (k & 15)) << 2) + (nrow & 3)]);
      k = k4 + 3;
      o.w = f2bf(tile[k * 72 + (((nrow >> 2) ^ (k & 15)) << 2) + (nrow & 3)]);
    }
    *(ushort4*)(out + (size_t)(c0 + nrow) * R + r0 + k4) = o;
  }
}

// ---------------------------------------------------------------------------
// RMSNorm over D=2048, one block (256 thr) per row.
// ---------------------------------------------------------------------------
template <int BF16OUT>
__global__ __launch_bounds__(256) void k_rmsnorm(const float* __restrict__ X,
                                                 const float* __restrict__ W,
                                                 void* __restrict__ OUT) {
  int row = blockIdx.x, tid = threadIdx.x;
  const float* xr = X + (size_t)row * DMODEL;
  f32x4 x0 = *(const f32x4*)(xr + tid * 4);
  f32x4 x1 = *(const f32x4*)(xr + 1024 + tid * 4);
  float ss = x0.x * x0.x + x0.y * x0.y + x0.z * x0.z + x0.w * x0.w +
             x1.x * x1.x + x1.y * x1.y + x1.z * x1.z + x1.w * x1.w;
#pragma unroll
  for (int o = 1; o < 64; o <<= 1) ss += __shfl_xor(ss, o, 64);
  __shared__ float red[4];
  int w = tid >> 6;
  if ((tid & 63) == 0) red[w] = ss;
  __syncthreads();
  float tot = red[0] + red[1] + red[2] + red[3];
  float sc = rsqrtf(tot / (float)DMODEL + 1e-6f);
  f32x4 w0 = *(const f32x4*)(W + tid * 4);
  f32x4 w1 = *(const f32x4*)(W + 1024 + tid * 4);
  if constexpr (BF16OUT) {
    ushort_t* o = (ushort_t*)OUT + (size_t)row * DMODEL;
    ushort4 a, b;
    a.x = f2bf(x0.x * sc * w0.x); a.y = f2bf(x0.y * sc * w0.y);
    a.z = f2bf(x0.z * sc * w0.z); a.w = f2bf(x0.w * sc * w0.w);
    b.x = f2bf(x1.x * sc * w1.x); b.y = f2bf(x1.y * sc * w1.y);
    b.z = f2bf(x1.z * sc * w1.z); b.w = f2bf(x1.w * sc * w1.w);
    *(ushort4*)(o + tid * 4) = a;
    *(ushort4*)(o + 1024 + tid * 4) = b;
  } else {
    float* o = (float*)OUT + (size_t)row * DMODEL;
    f32x4 a = {x0.x * sc * w0.x, x0.y * sc * w0.y, x0.z * sc * w0.z, x0.w * sc * w0.w};
    f32x4 b = {x1.x * sc * w1.x, x1.y * sc * w1.y, x1.z * sc * w1.z, x1.w * sc * w1.w};
    *(f32x4*)(o + tid * 4) = a;
    *(f32x4*)(o + 1024 + tid * 4) = b;
  }
}

// ---------------------------------------------------------------------------
// Reduce 4 split-K partials + residual: OUT[i] = RES[i] + sum_z P[z*n + i]
// ---------------------------------------------------------------------------
__global__ __launch_bounds__(256) void k_red4res(const float* __restrict__ P,
                                                 const float* __restrict__ RES,
                                                 float* __restrict__ OUT, int n) {
  int i = (blockIdx.x * 256 + threadIdx.x) * 4;
  if (i >= n) return;
  f32x4 v = *(const f32x4*)(RES + i);
#pragma unroll
  for (int z = 0; z < 4; ++z) {
    f32x4 t = *(const f32x4*)(P + (size_t)z * n + i);
    v.x += t.x; v.y += t.y; v.z += t.z; v.w += t.w;
  }
  *(f32x4*)(OUT + i) = v;
}

// ---------------------------------------------------------------------------
// 256x256 8-phase GEMM (T2 swizzle + T3/T4 counted vmcnt + T5 setprio).
// 8 waves 4Mx2N, BK=64, LDS 128KB double-buffered, 8 slots/tile of 64 rows.
// Split-K via blockIdx.z.  EPI: 0 store f32, 2 silu(GINB)*acc->bf16,
// 3 store bf16, 4 fused per-head RMSNorm+RoPE QKV epilogue.
// ---------------------------------------------------------------------------
#define EPI_STORE 0
#define EPI_SILU 2
#define EPI_STOREB 3
#define EPI_QKV 4

#define LOAD_B256(bs, rbase)                                                   \
  {                                                                            \
    _Pragma("unroll") for (int ks = 0; ks < 2; ++ks)                           \
        _Pragma("unroll") for (int ni = 0; ni < 2; ++ni)                       \
            bfr[ks][ni] = *(const bf16x8*)((bs) +                              \
                (((rbase) + ni * 16 + lr) << 6) +                              \
                ((((ks << 2) + lg) ^ (lr & 7)) << 3));                         \
  }

#define MFMA_Q256(q)                                                           \
  {                                                                            \
    _Pragma("unroll") for (int ks = 0; ks < 2; ++ks)                           \
        _Pragma("unroll") for (int mi = 0; mi < 4; ++mi)                       \
            _Pragma("unroll") for (int ni = 0; ni < 2; ++ni)                   \
                acc[mi][(q) * 2 + ni] =                                        \
                    __builtin_amdgcn_mfma_f32_16x16x32_bf16(                   \
                        af[ks][mi], bfr[ks][ni], acc[mi][(q) * 2 + ni], 0, 0, 0); \
  }

template <int LAST>
__device__ __forceinline__ void g256_iter(
    const ushort_t* __restrict__ as, const ushort_t* __restrict__ bsA,
    const ushort_t* __restrict__ bsB, ushort_t* __restrict__ nA,
    ushort_t* __restrict__ nB, const ushort_t* __restrict__ an,
    const ushort_t* __restrict__ bn, size_t rs, int slds, int lr, int lg,
    f32x4 (&acc)[4][8]) {
  bf16x8 af[2][4], bfr[2][2];
  // ---- P0 ----
#pragma unroll
  for (int ks = 0; ks < 2; ++ks)
#pragma unroll
    for (int mi = 0; mi < 4; ++mi)
      af[ks][mi] = *(const bf16x8*)(as + ((mi * 16 + lr) << 6) +
                                    ((((ks << 2) + lg) ^ (lr & 7)) << 3));
  LOAD_B256(bsA, 0);
  if constexpr (!LAST) {
    gload_lds16(an, nA + slds);
    gload_lds16(an + rs, nA + 4096 + slds);
  }
  __builtin_amdgcn_s_barrier();
  asm volatile("s_waitcnt lgkmcnt(0)" ::: "memory");
  __builtin_amdgcn_sched_barrier(0);
  __builtin_amdgcn_s_setprio(1);
  MFMA_Q256(0);
  __builtin_amdgcn_s_setprio(0);
  __builtin_amdgcn_s_barrier();
  // ---- P1 ----
  LOAD_B256(bsA, 32);
  if constexpr (!LAST) {
    gload_lds16(an + 2 * rs, nA + 8192 + slds);
    gload_lds16(an + 3 * rs, nA + 12288 + slds);
    asm volatile("s_waitcnt vmcnt(4)" ::: "memory");
  } else {
    asm volatile("s_waitcnt vmcnt(0)" ::: "memory");
  }
  __builtin_amdgcn_s_barrier();
  asm volatile("s_waitcnt lgkmcnt(0)" ::: "memory");
  __builtin_amdgcn_sched_barrier(0);
  __builtin_amdgcn_s_setprio(1);
  MFMA_Q256(1);
  __builtin_amdgcn_s_setprio(0);
  __builtin_amdgcn_s_barrier();
  // ---- P2 ----
  LOAD_B256(bsB, 0);
  if constexpr (!LAST) {
    gload_lds16(bn, nB + slds);
    gload_lds16(bn + 2 * rs, nB + 8192 + slds);
  }
  __builtin_amdgcn_s_barrier();
  asm volatile("s_waitcnt lgkmcnt(0)" ::: "memory");
  __builtin_amdgcn_sched_barrier(0);
  __builtin_amdgcn_s_setprio(1);
  MFMA_Q256(2);
  __builtin_amdgcn_s_setprio(0);
  __builtin_amdgcn_s_barrier();
  // ---- P3 ----
  LOAD_B256(bsB, 32);
  if constexpr (!LAST) {
    gload_lds16(bn + rs, nB + 4096 + slds);
    gload_lds16(bn + 3 * rs, nB + 12288 + slds);
    asm volatile("s_waitcnt vmcnt(2)" ::: "memory");
  }
  __builtin_amdgcn_s_barrier();
  asm volatile("s_waitcnt lgkmcnt(0)" ::: "memory");
  __builtin_amdgcn_sched_barrier(0);
  __builtin_amdgcn_s_setprio(1);
  MFMA_Q256(3);
  __builtin_amdgcn_s_setprio(0);
  __builtin_amdgcn_s_barrier();
}

template <int EPI>
__global__ __launch_bounds__(512, 2) void k_gemm256(
    const ushort_t* __restrict__ A, const ushort_t* __restrict__ BT,
    const ushort_t* __restrict__ GINB, float* __restrict__ CF,
    ushort_t* __restrict__ CB, int N, int Kstride, int Kc, size_t zoff,
    const float* __restrict__ QNW, const float* __restrict__ KNW,
    const int* __restrict__ POS, ushort_t* __restrict__ Qb,
    ushort_t* __restrict__ Kb, ushort_t* __restrict__ Vb) {
  __shared__ ushort_t lds[65536];  // 128 KiB
  const int tid = threadIdx.x;
  const int l = tid & 63, wid = tid >> 6;
  const int wm = wid >> 1, wn = wid & 1;
  const int lr = l & 15, lg = l >> 4;
  const int m0 = blockIdx.y * 256, n0 = blockIdx.x * 256;
  const int z = blockIdx.z;
  const int NT = Kc >> 6;

  A += (size_t)z * Kc;
  BT += (size_t)z * Kc;
  CF += (size_t)z * zoff;

  const int srow = tid >> 3;                    // 0..63 row within a slot
  const int scs = (tid & 7) ^ (srow & 7);       // pre-swizzled source chunk
  const size_t sgoff = (size_t)srow * Kstride + scs * 8;
  const int slds = wid * 512;                   // wave-uniform ushort offset

  const ushort_t* ga = A + (size_t)m0 * Kstride + sgoff;
  const ushort_t* gb = BT + (size_t)n0 * Kstride + sgoff;
  const size_t rs = (size_t)64 * Kstride;       // 64-row stride (elements)

  f32x4 acc[4][8] = {};

  ushort_t* Ab0 = lds;
  ushort_t* Bb0 = lds + 16384;
  ushort_t* Ab1 = lds + 32768;
  ushort_t* Bb1 = lds + 49152;

  // prologue: tile0 -> dbuf0, issue order A0,A1,A2,A3,B0,B2,B1,B3
  gload_lds16(ga, Ab0 + slds);
  gload_lds16(ga + rs, Ab0 + 4096 + slds);
  gload_lds16(ga + 2 * rs, Ab0 + 8192 + slds);
  gload_lds16(ga + 3 * rs, Ab0 + 12288 + slds);
  gload_lds16(gb, Bb0 + slds);
  gload_lds16(gb + 2 * rs, Bb0 + 8192 + slds);
  gload_lds16(gb + rs, Bb0 + 4096 + slds);
  gload_lds16(gb + 3 * rs, Bb0 + 12288 + slds);
  asm volatile("s_waitcnt vmcnt(2)" ::: "memory");
  __builtin_amdgcn_s_barrier();

  for (int kt = 0; kt < NT - 1; ++kt) {
    const int d = kt & 1;
    const ushort_t* as = (d ? Ab1 : Ab0) + wm * 4096;
    const ushort_t* bsA = (d ? Bb1 : Bb0) + (wn * 2) * 4096;
    ushort_t* nA = d ? Ab0 : Ab1;
    ushort_t* nB = d ? Bb0 : Bb1;
    g256_iter<0>(as, bsA, bsA + 4096, nA, nB, ga + (size_t)(kt + 1) * 64,
                 gb + (size_t)(kt + 1) * 64, rs, slds, lr, lg, acc);
  }
  {
    const int d = (NT - 1) & 1;
    const ushort_t* as = (d ? Ab1 : Ab0) + wm * 4096;
    const ushort_t* bsA = (d ? Bb1 : Bb0) + (wn * 2) * 4096;
    g256_iter<1>(as, bsA, bsA + 4096, nullptr, nullptr, nullptr, nullptr, rs,
                 slds, lr, lg, acc);
  }

  // ---- epilogue ----
  if constexpr (EPI == EPI_QKV) {
    // N=4096, BN=256: wave wn owns head = bx*2+wn (0-15 Q, 16-23 K, 24-31 V).
    const int head = (n0 >> 7) + wn;
    if (head < 24) {
      const float* nw = (head < 16) ? QNW : KNW;
      float w_lo[4], w_hi[4], ifr[4];
      const float k2c = 19.931568569324174f / 64.f;  // log2(1e6)/64
#pragma unroll
      for (int ci = 0; ci < 4; ++ci) {
        int dd = ci * 16 + lr;
        w_lo[ci] = nw[dd];
        w_hi[ci] = nw[dd + 64];
        ifr[ci] = exp2f(-(float)dd * k2c);
      }
#pragma unroll
      for (int mi = 0; mi < 4; ++mi)
#pragma unroll
        for (int rr = 0; rr < 4; ++rr) {
          int m = m0 + wm * 64 + mi * 16 + lg * 4 + rr;
          float vals[8];
          float ssum = 0.f;
#pragma unroll
          for (int ci = 0; ci < 8; ++ci) {
            vals[ci] = acc[mi][ci][rr];
            ssum += vals[ci] * vals[ci];
          }
#pragma unroll
          for (int o = 1; o < 16; o <<= 1) ssum += __shfl_xor(ssum, o, 64);
          float scn = rsqrtf(ssum * (1.f / 128.f) + 1e-6f);
          float pf = (float)POS[m];
          ushort_t o16[8];
#pragma unroll
          for (int ci = 0; ci < 4; ++ci) {
            float a = vals[ci] * scn * w_lo[ci];
            float b = vals[ci + 4] * scn * w_hi[ci];
            float th = pf * ifr[ci];
            float cs = cosf(th), sn = sinf(th);
            o16[ci] = f2bf(a * cs - b * sn);
            o16[ci + 4] = f2bf(b * cs + a * sn);
          }
          ushort_t* dst = (head < 16) ? (Qb + (size_t)m * 2048 + head * 128)
                                      : (Kb + (size_t)m * 1024 + (head - 16) * 128);
#pragma unroll
          for (int ci = 0; ci < 8; ++ci) dst[ci * 16 + lr] = o16[ci];
        }
    } else {
#pragma unroll
      for (int mi = 0; mi < 4; ++mi)
#pragma unroll
        for (int rr = 0; rr < 4; ++rr) {
          int m = m0 + wm * 64 + mi * 16 + lg * 4 + rr;
          ushort_t* dst = Vb + (size_t)m * 1024 + (head - 24) * 128;
#pragma unroll
          for (int ci = 0; ci < 8; ++ci) dst[ci * 16 + lr] = f2bf(acc[mi][ci][rr]);
        }
    }
  } else {
#pragma unroll
    for (int mi = 0; mi < 4; ++mi)
#pragma unroll
      for (int ci = 0; ci < 8; ++ci)
#pragma unroll
        for (int rr = 0; rr < 4; ++rr) {
          int m = m0 + wm * 64 + mi * 16 + lg * 4 + rr;
          int n = n0 + wn * 128 + ci * 16 + lr;
          size_t off = (size_t)m * N + n;
          float v = acc[mi][ci][rr];
          if constexpr (EPI == EPI_STORE) {
            CF[off] = v;
          } else if constexpr (EPI == EPI_STOREB) {
            CB[off] = f2bf(v);
          } else if constexpr (EPI == EPI_SILU) {
            float gv = bf2f(GINB[off]);
            float s = gv / (1.f + __expf(-gv));
            CB[off] = f2bf(s * v);
          }
        }
  }
}

// ---------------------------------------------------------------------------
// Flash attention, ragged causal mask.  1 wave per (16 q rows, KV head);
// both q-heads of the GQA group computed in-wave (shared K/V fragments).
// No __syncthreads: single-wave block, P-LDS roundtrip ordered by lgkmcnt
// only, so V/K global loads stay in flight across it.
// ---------------------------------------------------------------------------
__global__ __launch_bounds__(64) void k_flash(const ushort_t* __restrict__ Qb,
                                              const ushort_t* __restrict__ Kb,
                                              const ushort_t* __restrict__ VT,
                                              const int* __restrict__ SEG,
                                              ushort_t* __restrict__ Ob) {
  __shared__ ushort_t Pl[2][16 * 40];
  int l = threadIdx.x;
  int qt = blockIdx.x, kvh = blockIdx.y;
  int q0 = qt * 16;
  int lr = l & 15, lg = l >> 4;
  int h0 = kvh * 2;
  bf16x8 qf0[4], qf1[4];
  {
    const bf16x8* qv = (const bf16x8*)(Qb + (size_t)(q0 + lr) * 2048 + h0 * 128);
#pragma unroll
    for (int kk = 0; kk < 4; ++kk) {
      qf0[kk] = qv[kk * 4 + lg];
      qf1[kk] = qv[16 + kk * 4 + lg];
    }
  }
  int segq[4];
#pragma unroll
  for (int r = 0; r < 4; ++r) segq[r] = SEG[q0 + lg * 4 + r];
  int target = SEG[q0];
  int lo = 0, hi = q0;
  while (lo < hi) {
    int mid = (lo + hi) >> 1;
    if (SEG[mid] < target) lo = mid + 1; else hi = mid;
  }
  int s_start = lo & ~31;
  float mr[2][4], lrun[2][4];
  f32x4 acc[2][8] = {};
#pragma unroll
  for (int h = 0; h < 2; ++h)
#pragma unroll
    for (int r = 0; r < 4; ++r) { mr[h][r] = -1e30f; lrun[h][r] = 0.f; }
  const float scale = 0.08838834764831845f;  // 1/sqrt(128)
  for (int s0 = s_start; s0 < q0 + 16; s0 += 32) {
    int sa = s0 + lr, sb = s0 + 16 + lr;
    int sac = min(sa, T_SEQ - 1), sbc = min(sb, T_SEQ - 1);
    // V fragments issued early; consumed only after the P roundtrip.
    bf16x8 vfr[8];
    int sbase = min(s0 + lg * 8, T_SEQ - 8);
#pragma unroll
    for (int c = 0; c < 8; ++c)
      vfr[c] = *(const bf16x8*)(VT + (size_t)(kvh * 128 + c * 16 + lr) * T_SEQ + sbase);
    f32x4 SA0 = {}, SB0 = {}, SA1 = {}, SB1 = {};
    const bf16x8* ka = (const bf16x8*)(Kb + (size_t)sac * 1024 + kvh * 128);
    const bf16x8* kb_ = (const bf16x8*)(Kb + (size_t)sbc * 1024 + kvh * 128);
#pragma unroll
    for (int kk = 0; kk < 4; ++kk) {
      bf16x8 kaf = ka[kk * 4 + lg];
      bf16x8 kbf = kb_[kk * 4 + lg];
      SA0 = __builtin_amdgcn_mfma_f32_16x16x32_bf16(qf0[kk], kaf, SA0, 0, 0, 0);
      SB0 = __builtin_amdgcn_mfma_f32_16x16x32_bf16(qf0[kk], kbf, SB0, 0, 0, 0);
      SA1 = __builtin_amdgcn_mfma_f32_16x16x32_bf16(qf1[kk], kaf, SA1, 0, 0, 0);
      SB1 = __builtin_amdgcn_mfma_f32_16x16x32_bf16(qf1[kk], kbf, SB1, 0, 0, 0);
    }
    int sga = SEG[sac], sgb = SEG[sbc];
    bool mAv[4], mBv[4];
#pragma unroll
    for (int r = 0; r < 4; ++r) {
      int qrow = q0 + lg * 4 + r;
      mAv[r] = (sa <= qrow) && (sga == segq[r]);
      mBv[r] = (sb <= qrow) && (sgb == segq[r]);
    }
#pragma unroll
    for (int h = 0; h < 2; ++h) {
#pragma unroll
      for (int r = 0; r < 4; ++r) {
        float sva = (h ? SA1[r] : SA0[r]);
        float svb = (h ? SB1[r] : SB0[r]);
        float xa = mAv[r] ? sva * scale : -1e30f;
        float xb = mBv[r] ? svb * scale : -1e30f;
        float mx = fmaxf(xa, xb);
#pragma unroll
        for (int o = 1; o < 16; o <<= 1) mx = fmaxf(mx, __shfl_xor(mx, o, 64));
        float nm = fmaxf(mr[h][r], mx);
        float ea = __expf(xa - nm), eb = __expf(xb - nm);
        float rsum = ea + eb;
#pragma unroll
        for (int o = 1; o < 16; o <<= 1) rsum += __shfl_xor(rsum, o, 64);
        float al = __expf(mr[h][r] - nm);
        lrun[h][r] = lrun[h][r] * al + rsum;
        mr[h][r] = nm;
#pragma unroll
        for (int c = 0; c < 8; ++c) acc[h][c][r] *= al;
        Pl[h][(lg * 4 + r) * 40 + lr] = f2bf(ea);
        Pl[h][(lg * 4 + r) * 40 + 16 + lr] = f2bf(eb);
      }
    }
    // single-wave block: LDS ordering only (keeps global loads in flight)
    asm volatile("s_waitcnt lgkmcnt(0)" ::: "memory");
    bf16x8 pa0 = *(const bf16x8*)&Pl[0][lr * 40 + lg * 8];
    bf16x8 pa1 = *(const bf16x8*)&Pl[1][lr * 40 + lg * 8];
#pragma unroll
    for (int c = 0; c < 8; ++c) {
      acc[0][c] = __builtin_amdgcn_mfma_f32_16x16x32_bf16(pa0, vfr[c], acc[0][c], 0, 0, 0);
      acc[1][c] = __builtin_amdgcn_mfma_f32_16x16x32_bf16(pa1, vfr[c], acc[1][c], 0, 0, 0);
    }
  }
#pragma unroll
  for (int h = 0; h < 2; ++h)
#pragma unroll
    for (int c = 0; c < 8; ++c)
#pragma unroll
      for (int r = 0; r < 4; ++r) {
        float ov = acc[h][c][r] / lrun[h][r];
        Ob[(size_t)(q0 + lg * 4 + r) * 2048 + (h0 + h) * 128 + c * 16 + lr] = f2bf(ov);
      }
}

// ---------------------------------------------------------------------------
extern "C" void kernel_launch(void* const* d_in, const int* in_sizes, int n_in,
                              void* d_out, int out_size, void* d_ws, size_t ws_size,
                              hipStream_t stream) {
  const float* hidden = (const float*)d_in[0];
  const float* ln1 = (const float*)d_in[1];
  const float* ln2 = (const float*)d_in[2];
  const float* wq = (const float*)d_in[3];
  const float* wk = (const float*)d_in[4];
  const float* wv = (const float*)d_in[5];
  const float* wo = (const float*)d_in[6];
  const float* qnw = (const float*)d_in[7];
  const float* knw = (const float*)d_in[8];
  const float* wg = (const float*)d_in[9];
  const float* wu = (const float*)d_in[10];
  const float* wd = (const float*)d_in[11];
  const float* fnw = (const float*)d_in[12];
  const int* seg = (const int*)d_in[13];
  const int* pos = (const int*)d_in[14];
  float* out = (float*)d_out;

  char* ws = (char*)d_ws;
  size_t off = 0;
  auto alloc = [&](size_t bytes) {
    char* p = ws + off;
    off += (bytes + 255) & ~(size_t)255;
    return p;
  };
  ushort_t* wT = (ushort_t*)alloc((size_t)DFF * DMODEL * 2);       // rotating
  ushort_t* hbuf = (ushort_t*)alloc((size_t)T_SEQ * DMODEL * 2);
  ushort_t* qb = (ushort_t*)alloc((size_t)T_SEQ * 2048 * 2);
  ushort_t* kb = (ushort_t*)alloc((size_t)T_SEQ * 1024 * 2);
  ushort_t* vb = (ushort_t*)alloc((size_t)T_SEQ * 1024 * 2);
  ushort_t* vT = (ushort_t*)alloc((size_t)T_SEQ * 1024 * 2);
  ushort_t* ob = (ushort_t*)alloc((size_t)T_SEQ * 2048 * 2);
  float* gbufF = (float*)alloc((size_t)T_SEQ * DFF * 4);           // 67MB scratch
  ushort_t* gbufB = (ushort_t*)gbufF;                              // bf16 view
  ushort_t* mbuf = (ushort_t*)alloc((size_t)T_SEQ * DFF * 2);
  (void)ws_size; (void)in_sizes; (void)n_in; (void)out_size;

  dim3 b256(256), b64(64), b512(512);
  for (int lyr = 0; lyr < 2; ++lyr) {
    const float* xsrc = (lyr == 0) ? hidden : out;
    k_rmsnorm<1><<<T_SEQ, b256, 0, stream>>>(xsrc, ln1 + (size_t)lyr * DMODEL, hbuf);

    const float* wql = wq + (size_t)lyr * DMODEL * 2048;
    const float* wkl = wk + (size_t)lyr * DMODEL * 1024;
    const float* wvl = wv + (size_t)lyr * DMODEL * 1024;
    k_transpose_bf16<float><<<dim3(32, 32), b256, 0, stream>>>(wql, wT, 2048, 2048);
    k_transpose_bf16<float><<<dim3(16, 32), b256, 0, stream>>>(wkl, wT + (size_t)2048 * 2048, 2048, 1024);
    k_transpose_bf16<float><<<dim3(16, 32), b256, 0, stream>>>(wvl, wT + (size_t)3072 * 2048, 2048, 1024);
    // QKV GEMM with fused per-head RMSNorm + RoPE epilogue -> qb/kb/vb bf16
    k_gemm256<EPI_QKV><<<dim3(16, 8, 1), b512, 0, stream>>>(
        hbuf, wT, nullptr, nullptr, nullptr, 4096, 2048, 2048, 0,
        qnw + (size_t)lyr * 128, knw + (size_t)lyr * 128, pos, qb, kb, vb);
    k_transpose_bf16<ushort_t><<<dim3(16, 32), b256, 0, stream>>>(vb, vT, 2048, 1024);
    k_flash<<<dim3(T_SEQ / 16, NKV), b64, 0, stream>>>(qb, kb, vT, seg, ob);

    const float* wol = wo + (size_t)lyr * 2048 * DMODEL;
    k_transpose_bf16<float><<<dim3(32, 32), b256, 0, stream>>>(wol, wT, 2048, 2048);
    // WO split-K=4 (Kc=512): partials -> gbufF[z * 2048*2048], then +residual
    k_gemm256<EPI_STORE><<<dim3(8, 8, 4), b512, 0, stream>>>(
        ob, wT, nullptr, gbufF, nullptr, 2048, 2048, 512, (size_t)2048 * 2048,
        nullptr, nullptr, nullptr, nullptr, nullptr, nullptr);
    k_red4res<<<4096, b256, 0, stream>>>(gbufF, xsrc, out, 2048 * 2048);

    k_rmsnorm<1><<<T_SEQ, b256, 0, stream>>>(out, ln2 + (size_t)lyr * DMODEL, hbuf);

    const float* wgl = wg + (size_t)lyr * DMODEL * DFF;
    const float* wul = wu + (size_t)lyr * DMODEL * DFF;
    const float* wdl = wd + (size_t)lyr * DFF * DMODEL;
    k_transpose_bf16<float><<<dim3(128, 32), b256, 0, stream>>>(wgl, wT, 2048, 8192);
    k_gemm256<EPI_STOREB><<<dim3(32, 8, 1), b512, 0, stream>>>(
        hbuf, wT, nullptr, nullptr, gbufB, 8192, 2048, 2048, 0,
        nullptr, nullptr, nullptr, nullptr, nullptr, nullptr);
    k_transpose_bf16<float><<<dim3(128, 32), b256, 0, stream>>>(wul, wT, 2048, 8192);
    k_gemm256<EPI_SILU><<<dim3(32, 8, 1), b512, 0, stream>>>(
        hbuf, wT, gbufB, nullptr, mbuf, 8192, 2048, 2048, 0,
        nullptr, nullptr, nullptr, nullptr, nullptr, nullptr);
    k_transpose_bf16<float><<<dim3(32, 128), b256, 0, stream>>>(wdl, wT, 8192, 2048);
    // WD split-K=4 (Kc=2048): partials -> gbufF[z * 2048*2048], then +residual
    k_gemm256<EPI_STORE><<<dim3(8, 8, 4), b512, 0, stream>>>(
        mbuf, wT, nullptr, gbufF, nullptr, 2048, 8192, 2048, (size_t)2048 * 2048,
        nullptr, nullptr, nullptr, nullptr, nullptr, nullptr);
    k_red4res<<<4096, b256, 0, stream>>>(gbufF, out, out, 2048 * 2048);
  }
  k_rmsnorm<0><<<T_SEQ, b256, 0, stream>>>(out, fnw, out);
}

// Round 7
// 893.770 us; speedup vs baseline: 1.1885x; 1.1885x over previous
//
#include <hip/hip_runtime.h>
#include <stdint.h>

#define T_SEQ 2048
#define DMODEL 2048
#define NH 16
#define NKV 8
#define DHEAD 128
#define DFF 8192

typedef float f32x4 __attribute__((ext_vector_type(4)));
typedef float f32x2 __attribute__((ext_vector_type(2)));
typedef __bf16 bf16x8 __attribute__((ext_vector_type(8)));
typedef unsigned short ushort_t;

typedef __attribute__((address_space(1))) void gvoid;
typedef __attribute__((address_space(3))) void lvoid;

__device__ inline unsigned short f2bf(float f) {
  unsigned int u = __float_as_uint(f);
  u += 0x7fffu + ((u >> 16) & 1u);
  return (unsigned short)(u >> 16);
}
__device__ inline float bf2f(unsigned short h) {
  return __uint_as_float(((unsigned int)h) << 16);
}

__device__ inline void gload_lds16(const void* g, void* l) {
  // 16B per lane; LDS dest is wave-uniform base + lane*16 (HW rule)
  __builtin_amdgcn_global_load_lds((gvoid*)g, (lvoid*)l, 16, 0, 0);
}

// ---------------------------------------------------------------------------
// Transpose + convert: in f32/bf16 [R][C] -> out bf16 [C][R].  Tile 64x64.
// ---------------------------------------------------------------------------
template <typename TIN>
__global__ __launch_bounds__(256) void k_transpose_bf16(const TIN* __restrict__ in,
                                                        ushort_t* __restrict__ out,
                                                        int R, int C) {
  __shared__ float tile[64 * 72];
  int tid = threadIdx.x;
  int r0 = blockIdx.y * 64, c0 = blockIdx.x * 64;
  int rl = tid >> 4;   // 0..15
  int cc = tid & 15;   // 16B col chunk
#pragma unroll
  for (int i = 0; i < 4; ++i) {
    int row = rl + i * 16;
    const TIN* src = in + (size_t)(r0 + row) * C + c0 + cc * 4;
    float v0, v1, v2, v3;
    if constexpr (sizeof(TIN) == 4) {
      f32x4 v = *(const f32x4*)src;
      v0 = v.x; v1 = v.y; v2 = v.z; v3 = v.w;
    } else {
      ushort4 v = *(const ushort4*)src;
      v0 = bf2f(v.x); v1 = bf2f(v.y); v2 = bf2f(v.z); v3 = bf2f(v.w);
    }
    int chunk = cc ^ (row & 15);
    f32x4 t = {v0, v1, v2, v3};
    *(f32x4*)&tile[row * 72 + chunk * 4] = t;
  }
  __syncthreads();
#pragma unroll
  for (int i = 0; i < 4; ++i) {
    int nrow = rl + i * 16;   // output row local = input col
    int k4 = cc * 4;          // output col local base = input row
    ushort4 o;
    {
      int k = k4 + 0;
      o.x = f2bf(tile[k * 72 + (((nrow >> 2) ^ (k & 15)) << 2) + (nrow & 3)]);
      k = k4 + 1;
      o.y = f2bf(tile[k * 72 + (((nrow >> 2) ^ (k & 15)) << 2) + (nrow & 3)]);
      k = k4 + 2;
      o.z = f2bf(tile[k * 72 + (((nrow >> 2) ^ (k & 15)) << 2) + (nrow & 3)]);
      k = k4 + 3;
      o.w = f2bf(tile[k * 72 + (((nrow >> 2) ^ (k & 15)) << 2) + (nrow & 3)]);
    }
    *(ushort4*)(out + (size_t)(c0 + nrow) * R + r0 + k4) = o;
  }
}

// ---------------------------------------------------------------------------
// RMSNorm over D=2048, one block (256 thr) per row.
// ---------------------------------------------------------------------------
template <int BF16OUT>
__global__ __launch_bounds__(256) void k_rmsnorm(const float* __restrict__ X,
                                                 const float* __restrict__ W,
                                                 void* __restrict__ OUT) {
  int row = blockIdx.x, tid = threadIdx.x;
  const float* xr = X + (size_t)row * DMODEL;
  f32x4 x0 = *(const f32x4*)(xr + tid * 4);
  f32x4 x1 = *(const f32x4*)(xr + 1024 + tid * 4);
  float ss = x0.x * x0.x + x0.y * x0.y + x0.z * x0.z + x0.w * x0.w +
             x1.x * x1.x + x1.y * x1.y + x1.z * x1.z + x1.w * x1.w;
#pragma unroll
  for (int o = 1; o < 64; o <<= 1) ss += __shfl_xor(ss, o, 64);
  __shared__ float red[4];
  int w = tid >> 6;
  if ((tid & 63) == 0) red[w] = ss;
  __syncthreads();
  float tot = red[0] + red[1] + red[2] + red[3];
  float sc = rsqrtf(tot / (float)DMODEL + 1e-6f);
  f32x4 w0 = *(const f32x4*)(W + tid * 4);
  f32x4 w1 = *(const f32x4*)(W + 1024 + tid * 4);
  if constexpr (BF16OUT) {
    ushort_t* o = (ushort_t*)OUT + (size_t)row * DMODEL;
    ushort4 a, b;
    a.x = f2bf(x0.x * sc * w0.x); a.y = f2bf(x0.y * sc * w0.y);
    a.z = f2bf(x0.z * sc * w0.z); a.w = f2bf(x0.w * sc * w0.w);
    b.x = f2bf(x1.x * sc * w1.x); b.y = f2bf(x1.y * sc * w1.y);
    b.z = f2bf(x1.z * sc * w1.z); b.w = f2bf(x1.w * sc * w1.w);
    *(ushort4*)(o + tid * 4) = a;
    *(ushort4*)(o + 1024 + tid * 4) = b;
  } else {
    float* o = (float*)OUT + (size_t)row * DMODEL;
    f32x4 a = {x0.x * sc * w0.x, x0.y * sc * w0.y, x0.z * sc * w0.z, x0.w * sc * w0.w};
    f32x4 b = {x1.x * sc * w1.x, x1.y * sc * w1.y, x1.z * sc * w1.z, x1.w * sc * w1.w};
    *(f32x4*)(o + tid * 4) = a;
    *(f32x4*)(o + 1024 + tid * 4) = b;
  }
}

// ---------------------------------------------------------------------------
// Fused: OUT[row] = RES[row] + sum_z P_bf16[z][row]; optionally
// HB[row] = rmsnorm(OUT[row]) * W  (bf16).  One block (512 thr) per row.
// ---------------------------------------------------------------------------
template <int NZ, int WRITEH>
__global__ __launch_bounds__(512) void k_redln(const ushort_t* __restrict__ P,
                                               const float* __restrict__ RES,
                                               const float* __restrict__ W,
                                               float* __restrict__ OUT,
                                               ushort_t* __restrict__ HB) {
  int row = blockIdx.x, tid = threadIdx.x;
  size_t base = (size_t)row * DMODEL + tid * 4;
  f32x4 v = *(const f32x4*)(RES + base);
#pragma unroll
  for (int z = 0; z < NZ; ++z) {
    ushort4 t = *(const ushort4*)(P + (size_t)z * T_SEQ * DMODEL + base);
    v.x += bf2f(t.x); v.y += bf2f(t.y); v.z += bf2f(t.z); v.w += bf2f(t.w);
  }
  *(f32x4*)(OUT + base) = v;
  if constexpr (WRITEH) {
    float ss = v.x * v.x + v.y * v.y + v.z * v.z + v.w * v.w;
#pragma unroll
    for (int o = 1; o < 64; o <<= 1) ss += __shfl_xor(ss, o, 64);
    __shared__ float red[8];
    if ((tid & 63) == 0) red[tid >> 6] = ss;
    __syncthreads();
    float tot = 0.f;
#pragma unroll
    for (int i = 0; i < 8; ++i) tot += red[i];
    float sc = rsqrtf(tot / (float)DMODEL + 1e-6f);
    f32x4 wv = *(const f32x4*)(W + tid * 4);
    ushort4 h;
    h.x = f2bf(v.x * sc * wv.x); h.y = f2bf(v.y * sc * wv.y);
    h.z = f2bf(v.z * sc * wv.z); h.w = f2bf(v.w * sc * wv.w);
    *(ushort4*)(HB + base) = h;
  }
}

// ---------------------------------------------------------------------------
// 256x256 8-phase GEMM (T2 swizzle + T3/T4 counted vmcnt + T5 setprio).
// 8 waves 4Mx2N, BK=64, LDS 128KB double-buffered, 8 slots/tile of 64 rows.
// Split-K via blockIdx.z: z handles Kc cols, stores bf16 partial at CB+z*zoff.
// EPI: 2 silu(GINB)*acc->bf16, 3 store bf16.
// ---------------------------------------------------------------------------
#define EPI_SILU 2
#define EPI_STOREB 3

#define LOAD_B256(bs, rbase)                                                   \
  {                                                                            \
    _Pragma("unroll") for (int ks = 0; ks < 2; ++ks)                           \
        _Pragma("unroll") for (int ni = 0; ni < 2; ++ni)                       \
            bfr[ks][ni] = *(const bf16x8*)((bs) +                              \
                (((rbase) + ni * 16 + lr) << 6) +                              \
                ((((ks << 2) + lg) ^ (lr & 7)) << 3));                         \
  }

#define MFMA_Q256(q)                                                           \
  {                                                                            \
    _Pragma("unroll") for (int ks = 0; ks < 2; ++ks)                           \
        _Pragma("unroll") for (int mi = 0; mi < 4; ++mi)                       \
            _Pragma("unroll") for (int ni = 0; ni < 2; ++ni)                   \
                acc[mi][(q) * 2 + ni] =                                        \
                    __builtin_amdgcn_mfma_f32_16x16x32_bf16(                   \
                        af[ks][mi], bfr[ks][ni], acc[mi][(q) * 2 + ni], 0, 0, 0); \
  }

template <int LAST>
__device__ __forceinline__ void g256_iter(
    const ushort_t* __restrict__ as, const ushort_t* __restrict__ bsA,
    const ushort_t* __restrict__ bsB, ushort_t* __restrict__ nA,
    ushort_t* __restrict__ nB, const ushort_t* __restrict__ an,
    const ushort_t* __restrict__ bn, size_t rs, int slds, int lr, int lg,
    f32x4 (&acc)[4][8]) {
  bf16x8 af[2][4], bfr[2][2];
  // ---- P0 ----
#pragma unroll
  for (int ks = 0; ks < 2; ++ks)
#pragma unroll
    for (int mi = 0; mi < 4; ++mi)
      af[ks][mi] = *(const bf16x8*)(as + ((mi * 16 + lr) << 6) +
                                    ((((ks << 2) + lg) ^ (lr & 7)) << 3));
  LOAD_B256(bsA, 0);
  if constexpr (!LAST) {
    gload_lds16(an, nA + slds);
    gload_lds16(an + rs, nA + 4096 + slds);
  }
  __builtin_amdgcn_s_barrier();
  asm volatile("s_waitcnt lgkmcnt(0)" ::: "memory");
  __builtin_amdgcn_sched_barrier(0);
  __builtin_amdgcn_s_setprio(1);
  MFMA_Q256(0);
  __builtin_amdgcn_s_setprio(0);
  __builtin_amdgcn_s_barrier();
  // ---- P1 ----
  LOAD_B256(bsA, 32);
  if constexpr (!LAST) {
    gload_lds16(an + 2 * rs, nA + 8192 + slds);
    gload_lds16(an + 3 * rs, nA + 12288 + slds);
    asm volatile("s_waitcnt vmcnt(4)" ::: "memory");
  } else {
    asm volatile("s_waitcnt vmcnt(0)" ::: "memory");
  }
  __builtin_amdgcn_s_barrier();
  asm volatile("s_waitcnt lgkmcnt(0)" ::: "memory");
  __builtin_amdgcn_sched_barrier(0);
  __builtin_amdgcn_s_setprio(1);
  MFMA_Q256(1);
  __builtin_amdgcn_s_setprio(0);
  __builtin_amdgcn_s_barrier();
  // ---- P2 ----
  LOAD_B256(bsB, 0);
  if constexpr (!LAST) {
    gload_lds16(bn, nB + slds);
    gload_lds16(bn + 2 * rs, nB + 8192 + slds);
  }
  __builtin_amdgcn_s_barrier();
  asm volatile("s_waitcnt lgkmcnt(0)" ::: "memory");
  __builtin_amdgcn_sched_barrier(0);
  __builtin_amdgcn_s_setprio(1);
  MFMA_Q256(2);
  __builtin_amdgcn_s_setprio(0);
  __builtin_amdgcn_s_barrier();
  // ---- P3 ----
  LOAD_B256(bsB, 32);
  if constexpr (!LAST) {
    gload_lds16(bn + rs, nB + 4096 + slds);
    gload_lds16(bn + 3 * rs, nB + 12288 + slds);
    asm volatile("s_waitcnt vmcnt(2)" ::: "memory");
  }
  __builtin_amdgcn_s_barrier();
  asm volatile("s_waitcnt lgkmcnt(0)" ::: "memory");
  __builtin_amdgcn_sched_barrier(0);
  __builtin_amdgcn_s_setprio(1);
  MFMA_Q256(3);
  __builtin_amdgcn_s_setprio(0);
  __builtin_amdgcn_s_barrier();
}

template <int EPI>
__global__ __launch_bounds__(512, 2) void k_gemm256(
    const ushort_t* __restrict__ A, const ushort_t* __restrict__ BT,
    const ushort_t* __restrict__ GINB, ushort_t* __restrict__ CB,
    int N, int Kstride, int Kc, size_t zoff) {
  __shared__ ushort_t lds[65536];  // 128 KiB
  const int tid = threadIdx.x;
  const int l = tid & 63, wid = tid >> 6;
  const int wm = wid >> 1, wn = wid & 1;
  const int lr = l & 15, lg = l >> 4;
  const int m0 = blockIdx.y * 256, n0 = blockIdx.x * 256;
  const int z = blockIdx.z;
  const int NT = Kc >> 6;

  A += (size_t)z * Kc;
  BT += (size_t)z * Kc;
  CB += (size_t)z * zoff;

  const int srow = tid >> 3;                    // 0..63 row within a slot
  const int scs = (tid & 7) ^ (srow & 7);       // pre-swizzled source chunk
  const size_t sgoff = (size_t)srow * Kstride + scs * 8;
  const int slds = wid * 512;                   // wave-uniform ushort offset

  const ushort_t* ga = A + (size_t)m0 * Kstride + sgoff;
  const ushort_t* gb = BT + (size_t)n0 * Kstride + sgoff;
  const size_t rs = (size_t)64 * Kstride;       // 64-row stride (elements)

  f32x4 acc[4][8] = {};

  ushort_t* Ab0 = lds;
  ushort_t* Bb0 = lds + 16384;
  ushort_t* Ab1 = lds + 32768;
  ushort_t* Bb1 = lds + 49152;

  // prologue: tile0 -> dbuf0, issue order A0,A1,A2,A3,B0,B2,B1,B3
  gload_lds16(ga, Ab0 + slds);
  gload_lds16(ga + rs, Ab0 + 4096 + slds);
  gload_lds16(ga + 2 * rs, Ab0 + 8192 + slds);
  gload_lds16(ga + 3 * rs, Ab0 + 12288 + slds);
  gload_lds16(gb, Bb0 + slds);
  gload_lds16(gb + 2 * rs, Bb0 + 8192 + slds);
  gload_lds16(gb + rs, Bb0 + 4096 + slds);
  gload_lds16(gb + 3 * rs, Bb0 + 12288 + slds);
  asm volatile("s_waitcnt vmcnt(2)" ::: "memory");
  __builtin_amdgcn_s_barrier();

  for (int kt = 0; kt < NT - 1; ++kt) {
    const int d = kt & 1;
    const ushort_t* as = (d ? Ab1 : Ab0) + wm * 4096;
    const ushort_t* bsA = (d ? Bb1 : Bb0) + (wn * 2) * 4096;
    ushort_t* nA = d ? Ab0 : Ab1;
    ushort_t* nB = d ? Bb0 : Bb1;
    g256_iter<0>(as, bsA, bsA + 4096, nA, nB, ga + (size_t)(kt + 1) * 64,
                 gb + (size_t)(kt + 1) * 64, rs, slds, lr, lg, acc);
  }
  {
    const int d = (NT - 1) & 1;
    const ushort_t* as = (d ? Ab1 : Ab0) + wm * 4096;
    const ushort_t* bsA = (d ? Bb1 : Bb0) + (wn * 2) * 4096;
    g256_iter<1>(as, bsA, bsA + 4096, nullptr, nullptr, nullptr, nullptr, rs,
                 slds, lr, lg, acc);
  }

  // epilogue
#pragma unroll
  for (int mi = 0; mi < 4; ++mi)
#pragma unroll
    for (int ci = 0; ci < 8; ++ci)
#pragma unroll
      for (int rr = 0; rr < 4; ++rr) {
        int m = m0 + wm * 64 + mi * 16 + lg * 4 + rr;
        int n = n0 + wn * 128 + ci * 16 + lr;
        size_t off = (size_t)m * N + n;
        float v = acc[mi][ci][rr];
        if constexpr (EPI == EPI_STOREB) {
          CB[off] = f2bf(v);
        } else {
          float gv = bf2f(GINB[off]);
          float s = gv / (1.f + __expf(-gv));
          CB[off] = f2bf(s * v);
        }
      }
}

// ---------------------------------------------------------------------------
// Post-QKV: sum 2 bf16 split-K partials + per-head RMSNorm (q,k) + RoPE.
// ---------------------------------------------------------------------------
__global__ __launch_bounds__(256) void k_qkv_post(const ushort_t* __restrict__ Q0,
                                                  const ushort_t* __restrict__ Q1,
                                                  const float* __restrict__ QNW,
                                                  const float* __restrict__ KNW,
                                                  const int* __restrict__ POS,
                                                  ushort_t* __restrict__ Qb,
                                                  ushort_t* __restrict__ Kb,
                                                  ushort_t* __restrict__ Vb) {
  int t = blockIdx.x;
  int tid = threadIdx.x;
  int w = tid >> 6, l = tid & 63;
  float pos = (float)POS[t];
  const ushort_t* base0 = Q0 + (size_t)t * 4096;
  const ushort_t* base1 = Q1 + (size_t)t * 4096;
  int i0 = 2 * (l & 31);
  const float K2 = 19.931568569324174f / 64.f;  // log2(1e6)/64
  float ang0 = pos * exp2f(-(float)i0 * K2);
  float ang1 = pos * exp2f(-(float)(i0 + 1) * K2);
  float cs0 = cosf(ang0), sn0 = sinf(ang0);
  float cs1 = cosf(ang1), sn1 = sinf(ang1);
#pragma unroll
  for (int si = 0; si < 8; ++si) {
    int slot = w + si * 4;
    ushort2 xa = *(const ushort2*)(base0 + slot * 128 + l * 2);
    ushort2 xb = *(const ushort2*)(base1 + slot * 128 + l * 2);
    float v0 = bf2f(xa.x) + bf2f(xb.x), v1 = bf2f(xa.y) + bf2f(xb.y);
    float ss = v0 * v0 + v1 * v1;
#pragma unroll
    for (int o = 1; o < 64; o <<= 1) ss += __shfl_xor(ss, o, 64);
    if (slot < 24) {
      float sc = rsqrtf(ss / 128.f + 1e-6f);
      const float* wn = (slot < 16) ? QNW : KNW;
      f32x2 wv = *(const f32x2*)(wn + l * 2);
      v0 = v0 * sc * wv.x;
      v1 = v1 * sc * wv.y;
      float p0 = __shfl_xor(v0, 32, 64);
      float p1 = __shfl_xor(v1, 32, 64);
      float r0 = (l < 32) ? -p0 : p0;
      float r1 = (l < 32) ? -p1 : p1;
      v0 = v0 * cs0 + r0 * sn0;
      v1 = v1 * cs1 + r1 * sn1;
    }
    ushort2 uv;
    uv.x = f2bf(v0);
    uv.y = f2bf(v1);
    ushort_t* dst;
    if (slot < 16)
      dst = Qb + (size_t)t * 2048 + slot * 128 + l * 2;
    else if (slot < 24)
      dst = Kb + (size_t)t * 1024 + (slot - 16) * 128 + l * 2;
    else
      dst = Vb + (size_t)t * 1024 + (slot - 24) * 128 + l * 2;
    *(ushort2*)dst = uv;
  }
}

// ---------------------------------------------------------------------------
// Flash attention, ragged causal mask.  1 wave per (16 q rows, KV head);
// both q-heads of the GQA group computed in-wave (shared K/V fragments).
// No __syncthreads: single-wave block, P-LDS roundtrip ordered by lgkmcnt.
// ---------------------------------------------------------------------------
__global__ __launch_bounds__(64) void k_flash(const ushort_t* __restrict__ Qb,
                                              const ushort_t* __restrict__ Kb,
                                              const ushort_t* __restrict__ VT,
                                              const int* __restrict__ SEG,
                                              ushort_t* __restrict__ Ob) {
  __shared__ ushort_t Pl[2][16 * 40];
  int l = threadIdx.x;
  int qt = blockIdx.x, kvh = blockIdx.y;
  int q0 = qt * 16;
  int lr = l & 15, lg = l >> 4;
  int h0 = kvh * 2;
  bf16x8 qf0[4], qf1[4];
  {
    const bf16x8* qv = (const bf16x8*)(Qb + (size_t)(q0 + lr) * 2048 + h0 * 128);
#pragma unroll
    for (int kk = 0; kk < 4; ++kk) {
      qf0[kk] = qv[kk * 4 + lg];
      qf1[kk] = qv[16 + kk * 4 + lg];
    }
  }
  int segq[4];
#pragma unroll
  for (int r = 0; r < 4; ++r) segq[r] = SEG[q0 + lg * 4 + r];
  int target = SEG[q0];
  int lo = 0, hi = q0;
  while (lo < hi) {
    int mid = (lo + hi) >> 1;
    if (SEG[mid] < target) lo = mid + 1; else hi = mid;
  }
  int s_start = lo & ~31;
  float mr[2][4], lrun[2][4];
  f32x4 acc[2][8] = {};
#pragma unroll
  for (int h = 0; h < 2; ++h)
#pragma unroll
    for (int r = 0; r < 4; ++r) { mr[h][r] = -1e30f; lrun[h][r] = 0.f; }
  const float scale = 0.08838834764831845f;  // 1/sqrt(128)
  for (int s0 = s_start; s0 < q0 + 16; s0 += 32) {
    int sa = s0 + lr, sb = s0 + 16 + lr;
    int sac = min(sa, T_SEQ - 1), sbc = min(sb, T_SEQ - 1);
    // V fragments issued early; consumed only after the P roundtrip.
    bf16x8 vfr[8];
    int sbase = min(s0 + lg * 8, T_SEQ - 8);
#pragma unroll
    for (int c = 0; c < 8; ++c)
      vfr[c] = *(const bf16x8*)(VT + (size_t)(kvh * 128 + c * 16 + lr) * T_SEQ + sbase);
    f32x4 SA0 = {}, SB0 = {}, SA1 = {}, SB1 = {};
    const bf16x8* ka = (const bf16x8*)(Kb + (size_t)sac * 1024 + kvh * 128);
    const bf16x8* kb_ = (const bf16x8*)(Kb + (size_t)sbc * 1024 + kvh * 128);
#pragma unroll
    for (int kk = 0; kk < 4; ++kk) {
      bf16x8 kaf = ka[kk * 4 + lg];
      bf16x8 kbf = kb_[kk * 4 + lg];
      SA0 = __builtin_amdgcn_mfma_f32_16x16x32_bf16(qf0[kk], kaf, SA0, 0, 0, 0);
      SB0 = __builtin_amdgcn_mfma_f32_16x16x32_bf16(qf0[kk], kbf, SB0, 0, 0, 0);
      SA1 = __builtin_amdgcn_mfma_f32_16x16x32_bf16(qf1[kk], kaf, SA1, 0, 0, 0);
      SB1 = __builtin_amdgcn_mfma_f32_16x16x32_bf16(qf1[kk], kbf, SB1, 0, 0, 0);
    }
    int sga = SEG[sac], sgb = SEG[sbc];
    bool mAv[4], mBv[4];
#pragma unroll
    for (int r = 0; r < 4; ++r) {
      int qrow = q0 + lg * 4 + r;
      mAv[r] = (sa <= qrow) && (sga == segq[r]);
      mBv[r] = (sb <= qrow) && (sgb == segq[r]);
    }
#pragma unroll
    for (int h = 0; h < 2; ++h) {
#pragma unroll
      for (int r = 0; r < 4; ++r) {
        float sva = (h ? SA1[r] : SA0[r]);
        float svb = (h ? SB1[r] : SB0[r]);
        float xa = mAv[r] ? sva * scale : -1e30f;
        float xb = mBv[r] ? svb * scale : -1e30f;
        float mx = fmaxf(xa, xb);
#pragma unroll
        for (int o = 1; o < 16; o <<= 1) mx = fmaxf(mx, __shfl_xor(mx, o, 64));
        float nm = fmaxf(mr[h][r], mx);
        float ea = __expf(xa - nm), eb = __expf(xb - nm);
        float rsum = ea + eb;
#pragma unroll
        for (int o = 1; o < 16; o <<= 1) rsum += __shfl_xor(rsum, o, 64);
        float al = __expf(mr[h][r] - nm);
        lrun[h][r] = lrun[h][r] * al + rsum;
        mr[h][r] = nm;
#pragma unroll
        for (int c = 0; c < 8; ++c) acc[h][c][r] *= al;
        Pl[h][(lg * 4 + r) * 40 + lr] = f2bf(ea);
        Pl[h][(lg * 4 + r) * 40 + 16 + lr] = f2bf(eb);
      }
    }
    // single-wave block: LDS ordering only (keeps global loads in flight)
    asm volatile("s_waitcnt lgkmcnt(0)" ::: "memory");
    bf16x8 pa0 = *(const bf16x8*)&Pl[0][lr * 40 + lg * 8];
    bf16x8 pa1 = *(const bf16x8*)&Pl[1][lr * 40 + lg * 8];
#pragma unroll
    for (int c = 0; c < 8; ++c) {
      acc[0][c] = __builtin_amdgcn_mfma_f32_16x16x32_bf16(pa0, vfr[c], acc[0][c], 0, 0, 0);
      acc[1][c] = __builtin_amdgcn_mfma_f32_16x16x32_bf16(pa1, vfr[c], acc[1][c], 0, 0, 0);
    }
  }
#pragma unroll
  for (int h = 0; h < 2; ++h)
#pragma unroll
    for (int c = 0; c < 8; ++c)
#pragma unroll
      for (int r = 0; r < 4; ++r) {
        float ov = acc[h][c][r] / lrun[h][r];
        Ob[(size_t)(q0 + lg * 4 + r) * 2048 + (h0 + h) * 128 + c * 16 + lr] = f2bf(ov);
      }
}

// ---------------------------------------------------------------------------
extern "C" void kernel_launch(void* const* d_in, const int* in_sizes, int n_in,
                              void* d_out, int out_size, void* d_ws, size_t ws_size,
                              hipStream_t stream) {
  const float* hidden = (const float*)d_in[0];
  const float* ln1 = (const float*)d_in[1];
  const float* ln2 = (const float*)d_in[2];
  const float* wq = (const float*)d_in[3];
  const float* wk = (const float*)d_in[4];
  const float* wv = (const float*)d_in[5];
  const float* wo = (const float*)d_in[6];
  const float* qnw = (const float*)d_in[7];
  const float* knw = (const float*)d_in[8];
  const float* wg = (const float*)d_in[9];
  const float* wu = (const float*)d_in[10];
  const float* wd = (const float*)d_in[11];
  const float* fnw = (const float*)d_in[12];
  const int* seg = (const int*)d_in[13];
  const int* pos = (const int*)d_in[14];
  float* out = (float*)d_out;

  char* ws = (char*)d_ws;
  size_t off = 0;
  auto alloc = [&](size_t bytes) {
    char* p = ws + off;
    off += (bytes + 255) & ~(size_t)255;
    return p;
  };
  ushort_t* wT = (ushort_t*)alloc((size_t)DFF * DMODEL * 2);       // rotating
  ushort_t* hbuf = (ushort_t*)alloc((size_t)T_SEQ * DMODEL * 2);
  ushort_t* qb = (ushort_t*)alloc((size_t)T_SEQ * 2048 * 2);
  ushort_t* kb = (ushort_t*)alloc((size_t)T_SEQ * 1024 * 2);
  ushort_t* vb = (ushort_t*)alloc((size_t)T_SEQ * 1024 * 2);
  ushort_t* vT = (ushort_t*)alloc((size_t)T_SEQ * 1024 * 2);
  ushort_t* ob = (ushort_t*)alloc((size_t)T_SEQ * 2048 * 2);
  ushort_t* qkvp = (ushort_t*)alloc((size_t)2 * T_SEQ * 4096 * 2); // bf16 partials
  ushort_t* pbuf = (ushort_t*)alloc((size_t)4 * T_SEQ * DMODEL * 2);
  ushort_t* gbufB = (ushort_t*)alloc((size_t)T_SEQ * DFF * 2);
  ushort_t* mbuf = (ushort_t*)alloc((size_t)T_SEQ * DFF * 2);
  (void)ws_size; (void)in_sizes; (void)n_in; (void)out_size;

  dim3 b256(256), b64(64), b512(512);
  // layer-0 input norm
  k_rmsnorm<1><<<T_SEQ, b256, 0, stream>>>(hidden, ln1, hbuf);

  for (int lyr = 0; lyr < 2; ++lyr) {
    const float* xsrc = (lyr == 0) ? hidden : out;

    const float* wql = wq + (size_t)lyr * DMODEL * 2048;
    const float* wkl = wk + (size_t)lyr * DMODEL * 1024;
    const float* wvl = wv + (size_t)lyr * DMODEL * 1024;
    k_transpose_bf16<float><<<dim3(32, 32), b256, 0, stream>>>(wql, wT, 2048, 2048);
    k_transpose_bf16<float><<<dim3(16, 32), b256, 0, stream>>>(wkl, wT + (size_t)2048 * 2048, 2048, 1024);
    k_transpose_bf16<float><<<dim3(16, 32), b256, 0, stream>>>(wvl, wT + (size_t)3072 * 2048, 2048, 1024);
    // QKV split-K=2 (Kc=1024): bf16 partials -> qkvp[z * 2048*4096]
    k_gemm256<EPI_STOREB><<<dim3(16, 8, 2), b512, 0, stream>>>(
        hbuf, wT, nullptr, qkvp, 4096, 2048, 1024, (size_t)2048 * 4096);
    k_qkv_post<<<T_SEQ, b256, 0, stream>>>(qkvp, qkvp + (size_t)2048 * 4096,
                                           qnw + (size_t)lyr * 128, knw + (size_t)lyr * 128,
                                           pos, qb, kb, vb);
    k_transpose_bf16<ushort_t><<<dim3(16, 32), b256, 0, stream>>>(vb, vT, 2048, 1024);
    k_flash<<<dim3(T_SEQ / 16, NKV), b64, 0, stream>>>(qb, kb, vT, seg, ob);

    const float* wol = wo + (size_t)lyr * 2048 * DMODEL;
    k_transpose_bf16<float><<<dim3(32, 32), b256, 0, stream>>>(wol, wT, 2048, 2048);
    // WO split-K=4 (Kc=512): bf16 partials, then fused residual+reduce+ln2
    k_gemm256<EPI_STOREB><<<dim3(8, 8, 4), b512, 0, stream>>>(
        ob, wT, nullptr, pbuf, 2048, 2048, 512, (size_t)2048 * 2048);
    k_redln<4, 1><<<T_SEQ, b512, 0, stream>>>(pbuf, xsrc,
                                              ln2 + (size_t)lyr * DMODEL, out, hbuf);

    const float* wgl = wg + (size_t)lyr * DMODEL * DFF;
    const float* wul = wu + (size_t)lyr * DMODEL * DFF;
    const float* wdl = wd + (size_t)lyr * DFF * DMODEL;
    k_transpose_bf16<float><<<dim3(128, 32), b256, 0, stream>>>(wgl, wT, 2048, 8192);
    k_gemm256<EPI_STOREB><<<dim3(32, 8, 1), b512, 0, stream>>>(
        hbuf, wT, nullptr, gbufB, 8192, 2048, 2048, 0);
    k_transpose_bf16<float><<<dim3(128, 32), b256, 0, stream>>>(wul, wT, 2048, 8192);
    k_gemm256<EPI_SILU><<<dim3(32, 8, 1), b512, 0, stream>>>(
        hbuf, wT, gbufB, mbuf, 8192, 2048, 2048, 0);
    k_transpose_bf16<float><<<dim3(32, 128), b256, 0, stream>>>(wdl, wT, 8192, 2048);
    // WD split-K=4 (Kc=2048): bf16 partials, fused residual+reduce(+next ln1)
    k_gemm256<EPI_STOREB><<<dim3(8, 8, 4), b512, 0, stream>>>(
        mbuf, wT, nullptr, pbuf, 2048, 8192, 2048, (size_t)2048 * 2048);
    if (lyr == 0) {
      k_redln<4, 1><<<T_SEQ, b512, 0, stream>>>(pbuf, out, ln1 + DMODEL, out, hbuf);
    } else {
      k_redln<4, 0><<<T_SEQ, b512, 0, stream>>>(pbuf, out, nullptr, out, nullptr);
    }
  }
  k_rmsnorm<0><<<T_SEQ, b256, 0, stream>>>(out, fnw, out);
}

// Round 9
// 872.412 us; speedup vs baseline: 1.2175x; 1.0245x over previous
//
#include <hip/hip_runtime.h>
#include <stdint.h>

#define T_SEQ 2048
#define DMODEL 2048
#define NH 16
#define NKV 8
#define DHEAD 128
#define DFF 8192

typedef float f32x4 __attribute__((ext_vector_type(4)));
typedef float f32x2 __attribute__((ext_vector_type(2)));
typedef __bf16 bf16x8 __attribute__((ext_vector_type(8)));
typedef unsigned short ushort_t;

typedef __attribute__((address_space(1))) void gvoid;
typedef __attribute__((address_space(3))) void lvoid;

__device__ inline unsigned short f2bf(float f) {
  unsigned int u = __float_as_uint(f);
  u += 0x7fffu + ((u >> 16) & 1u);
  return (unsigned short)(u >> 16);
}
__device__ inline float bf2f(unsigned short h) {
  return __uint_as_float(((unsigned int)h) << 16);
}

__device__ inline void gload_lds16(const void* g, void* l) {
  // 16B per lane; LDS dest is wave-uniform base + lane*16 (HW rule)
  __builtin_amdgcn_global_load_lds((gvoid*)g, (lvoid*)l, 16, 0, 0);
}

// ---------------------------------------------------------------------------
// Transpose + convert: in f32/bf16 [R][C] -> out bf16 [C][R].  Tile 64x64.
// ---------------------------------------------------------------------------
template <typename TIN>
__global__ __launch_bounds__(256) void k_transpose_bf16(const TIN* __restrict__ in,
                                                        ushort_t* __restrict__ out,
                                                        int R, int C) {
  __shared__ float tile[64 * 72];
  int tid = threadIdx.x;
  int r0 = blockIdx.y * 64, c0 = blockIdx.x * 64;
  int rl = tid >> 4;   // 0..15
  int cc = tid & 15;   // 16B col chunk
#pragma unroll
  for (int i = 0; i < 4; ++i) {
    int row = rl + i * 16;
    const TIN* src = in + (size_t)(r0 + row) * C + c0 + cc * 4;
    float v0, v1, v2, v3;
    if constexpr (sizeof(TIN) == 4) {
      f32x4 v = *(const f32x4*)src;
      v0 = v.x; v1 = v.y; v2 = v.z; v3 = v.w;
    } else {
      ushort4 v = *(const ushort4*)src;
      v0 = bf2f(v.x); v1 = bf2f(v.y); v2 = bf2f(v.z); v3 = bf2f(v.w);
    }
    int chunk = cc ^ (row & 15);
    f32x4 t = {v0, v1, v2, v3};
    *(f32x4*)&tile[row * 72 + chunk * 4] = t;
  }
  __syncthreads();
#pragma unroll
  for (int i = 0; i < 4; ++i) {
    int nrow = rl + i * 16;   // output row local = input col
    int k4 = cc * 4;          // output col local base = input row
    ushort4 o;
    {
      int k = k4 + 0;
      o.x = f2bf(tile[k * 72 + (((nrow >> 2) ^ (k & 15)) << 2) + (nrow & 3)]);
      k = k4 + 1;
      o.y = f2bf(tile[k * 72 + (((nrow >> 2) ^ (k & 15)) << 2) + (nrow & 3)]);
      k = k4 + 2;
      o.z = f2bf(tile[k * 72 + (((nrow >> 2) ^ (k & 15)) << 2) + (nrow & 3)]);
      k = k4 + 3;
      o.w = f2bf(tile[k * 72 + (((nrow >> 2) ^ (k & 15)) << 2) + (nrow & 3)]);
    }
    *(ushort4*)(out + (size_t)(c0 + nrow) * R + r0 + k4) = o;
  }
}

// ---------------------------------------------------------------------------
// RMSNorm over D=2048, one block (256 thr) per row.
// ---------------------------------------------------------------------------
template <int BF16OUT>
__global__ __launch_bounds__(256) void k_rmsnorm(const float* __restrict__ X,
                                                 const float* __restrict__ W,
                                                 void* __restrict__ OUT) {
  int row = blockIdx.x, tid = threadIdx.x;
  const float* xr = X + (size_t)row * DMODEL;
  f32x4 x0 = *(const f32x4*)(xr + tid * 4);
  f32x4 x1 = *(const f32x4*)(xr + 1024 + tid * 4);
  float ss = x0.x * x0.x + x0.y * x0.y + x0.z * x0.z + x0.w * x0.w +
             x1.x * x1.x + x1.y * x1.y + x1.z * x1.z + x1.w * x1.w;
#pragma unroll
  for (int o = 1; o < 64; o <<= 1) ss += __shfl_xor(ss, o, 64);
  __shared__ float red[4];
  int w = tid >> 6;
  if ((tid & 63) == 0) red[w] = ss;
  __syncthreads();
  float tot = red[0] + red[1] + red[2] + red[3];
  float sc = rsqrtf(tot / (float)DMODEL + 1e-6f);
  f32x4 w0 = *(const f32x4*)(W + tid * 4);
  f32x4 w1 = *(const f32x4*)(W + 1024 + tid * 4);
  if constexpr (BF16OUT) {
    ushort_t* o = (ushort_t*)OUT + (size_t)row * DMODEL;
    ushort4 a, b;
    a.x = f2bf(x0.x * sc * w0.x); a.y = f2bf(x0.y * sc * w0.y);
    a.z = f2bf(x0.z * sc * w0.z); a.w = f2bf(x0.w * sc * w0.w);
    b.x = f2bf(x1.x * sc * w1.x); b.y = f2bf(x1.y * sc * w1.y);
    b.z = f2bf(x1.z * sc * w1.z); b.w = f2bf(x1.w * sc * w1.w);
    *(ushort4*)(o + tid * 4) = a;
    *(ushort4*)(o + 1024 + tid * 4) = b;
  } else {
    float* o = (float*)OUT + (size_t)row * DMODEL;
    f32x4 a = {x0.x * sc * w0.x, x0.y * sc * w0.y, x0.z * sc * w0.z, x0.w * sc * w0.w};
    f32x4 b = {x1.x * sc * w1.x, x1.y * sc * w1.y, x1.z * sc * w1.z, x1.w * sc * w1.w};
    *(f32x4*)(o + tid * 4) = a;
    *(f32x4*)(o + 1024 + tid * 4) = b;
  }
}

// ---------------------------------------------------------------------------
// Fused: OUT[row] = RES[row] + sum_z P_bf16[z][row]; optionally
// HB[row] = rmsnorm(OUT[row]) * W  (bf16).  One block (512 thr) per row.
// ---------------------------------------------------------------------------
template <int NZ, int WRITEH>
__global__ __launch_bounds__(512) void k_redln(const ushort_t* __restrict__ P,
                                               const float* __restrict__ RES,
                                               const float* __restrict__ W,
                                               float* __restrict__ OUT,
                                               ushort_t* __restrict__ HB) {
  int row = blockIdx.x, tid = threadIdx.x;
  size_t base = (size_t)row * DMODEL + tid * 4;
  f32x4 v = *(const f32x4*)(RES + base);
#pragma unroll
  for (int z = 0; z < NZ; ++z) {
    ushort4 t = *(const ushort4*)(P + (size_t)z * T_SEQ * DMODEL + base);
    v.x += bf2f(t.x); v.y += bf2f(t.y); v.z += bf2f(t.z); v.w += bf2f(t.w);
  }
  *(f32x4*)(OUT + base) = v;
  if constexpr (WRITEH) {
    float ss = v.x * v.x + v.y * v.y + v.z * v.z + v.w * v.w;
#pragma unroll
    for (int o = 1; o < 64; o <<= 1) ss += __shfl_xor(ss, o, 64);
    __shared__ float red[8];
    if ((tid & 63) == 0) red[tid >> 6] = ss;
    __syncthreads();
    float tot = 0.f;
#pragma unroll
    for (int i = 0; i < 8; ++i) tot += red[i];
    float sc = rsqrtf(tot / (float)DMODEL + 1e-6f);
    f32x4 wv = *(const f32x4*)(W + tid * 4);
    ushort4 h;
    h.x = f2bf(v.x * sc * wv.x); h.y = f2bf(v.y * sc * wv.y);
    h.z = f2bf(v.z * sc * wv.z); h.w = f2bf(v.w * sc * wv.w);
    *(ushort4*)(HB + base) = h;
  }
}

// ---------------------------------------------------------------------------
// 256x256 8-phase GEMM (T2 swizzle + T3/T4 counted vmcnt + T5 setprio).
// 8 waves 4Mx2N, BK=64, LDS 128KB double-buffered, 8 slots/tile of 64 rows.
// Stage issue (for t+1): P0: A0,A1,B0,B2   P1: A2,A3,B1,B3.
// Waits: vmcnt(8) @P1 (drains PREV tile's B1,B3 — issued 4 phases ago),
//        vmcnt(2) @P3 (drains this tile's 6 P0/P1 loads — 2-3 phases ago).
// XCD-bijective block swizzle: each XCD gets one contiguous by-row chunk.
// Split-K via blockIdx.z.  EPI: 2 silu(GINB)*acc->bf16, 3 store bf16.
// ---------------------------------------------------------------------------
#define EPI_SILU 2
#define EPI_STOREB 3

#define LOAD_B256(bs, rbase)                                                   \
  {                                                                            \
    _Pragma("unroll") for (int ks = 0; ks < 2; ++ks)                           \
        _Pragma("unroll") for (int ni = 0; ni < 2; ++ni)                       \
            bfr[ks][ni] = *(const bf16x8*)((bs) +                              \
                (((rbase) + ni * 16 + lr) << 6) +                              \
                ((((ks << 2) + lg) ^ (lr & 7)) << 3));                         \
  }

#define MFMA_Q256(q)                                                           \
  {                                                                            \
    _Pragma("unroll") for (int ks = 0; ks < 2; ++ks)                           \
        _Pragma("unroll") for (int mi = 0; mi < 4; ++mi)                       \
            _Pragma("unroll") for (int ni = 0; ni < 2; ++ni)                   \
                acc[mi][(q) * 2 + ni] =                                        \
                    __builtin_amdgcn_mfma_f32_16x16x32_bf16(                   \
                        af[ks][mi], bfr[ks][ni], acc[mi][(q) * 2 + ni], 0, 0, 0); \
  }

template <int LAST>
__device__ __forceinline__ void g256_iter(
    const ushort_t* __restrict__ as, const ushort_t* __restrict__ bsA,
    const ushort_t* __restrict__ bsB, ushort_t* __restrict__ nA,
    ushort_t* __restrict__ nB, const ushort_t* __restrict__ an,
    const ushort_t* __restrict__ bn, size_t rs, int slds, int lr, int lg,
    f32x4 (&acc)[4][8]) {
  bf16x8 af[2][4], bfr[2][2];
  // ---- P0: ds-read A frags + B(slot lo, rows 0-31); issue A0,A1,B0,B2 ----
#pragma unroll
  for (int ks = 0; ks < 2; ++ks)
#pragma unroll
    for (int mi = 0; mi < 4; ++mi)
      af[ks][mi] = *(const bf16x8*)(as + ((mi * 16 + lr) << 6) +
                                    ((((ks << 2) + lg) ^ (lr & 7)) << 3));
  LOAD_B256(bsA, 0);
  if constexpr (!LAST) {
    gload_lds16(an, nA + slds);
    gload_lds16(an + rs, nA + 4096 + slds);
    gload_lds16(bn, nB + slds);
    gload_lds16(bn + 2 * rs, nB + 8192 + slds);
  }
  __builtin_amdgcn_s_barrier();
  asm volatile("s_waitcnt lgkmcnt(0)" ::: "memory");
  __builtin_amdgcn_sched_barrier(0);
  __builtin_amdgcn_s_setprio(1);
  MFMA_Q256(0);
  __builtin_amdgcn_s_setprio(0);
  __builtin_amdgcn_s_barrier();
  // ---- P1: issue A2,A3,B1,B3; wait for PREV tile's B1,B3 ----
  LOAD_B256(bsA, 32);
  if constexpr (!LAST) {
    gload_lds16(an + 2 * rs, nA + 8192 + slds);
    gload_lds16(an + 3 * rs, nA + 12288 + slds);
    gload_lds16(bn + rs, nB + 4096 + slds);
    gload_lds16(bn + 3 * rs, nB + 12288 + slds);
    asm volatile("s_waitcnt vmcnt(8)" ::: "memory");
  } else {
    asm volatile("s_waitcnt vmcnt(0)" ::: "memory");
  }
  __builtin_amdgcn_s_barrier();
  asm volatile("s_waitcnt lgkmcnt(0)" ::: "memory");
  __builtin_amdgcn_sched_barrier(0);
  __builtin_amdgcn_s_setprio(1);
  MFMA_Q256(1);
  __builtin_amdgcn_s_setprio(0);
  __builtin_amdgcn_s_barrier();
  // ---- P2 ----
  LOAD_B256(bsB, 0);
  __builtin_amdgcn_s_barrier();
  asm volatile("s_waitcnt lgkmcnt(0)" ::: "memory");
  __builtin_amdgcn_sched_barrier(0);
  __builtin_amdgcn_s_setprio(1);
  MFMA_Q256(2);
  __builtin_amdgcn_s_setprio(0);
  __builtin_amdgcn_s_barrier();
  // ---- P3: wait for this tile's A0-3,B0,B2 (issued 2-3 phases ago) ----
  LOAD_B256(bsB, 32);
  if constexpr (!LAST) {
    asm volatile("s_waitcnt vmcnt(2)" ::: "memory");
  }
  __builtin_amdgcn_s_barrier();
  asm volatile("s_waitcnt lgkmcnt(0)" ::: "memory");
  __builtin_amdgcn_sched_barrier(0);
  __builtin_amdgcn_s_setprio(1);
  MFMA_Q256(3);
  __builtin_amdgcn_s_setprio(0);
  __builtin_amdgcn_s_barrier();
}

template <int EPI>
__global__ __launch_bounds__(512, 2) void k_gemm256(
    const ushort_t* __restrict__ A, const ushort_t* __restrict__ BT,
    const ushort_t* __restrict__ GINB, ushort_t* __restrict__ CB,
    int N, int Kstride, int Kc, size_t zoff) {
  __shared__ ushort_t lds[65536];  // 128 KiB
  const int tid = threadIdx.x;
  const int l = tid & 63, wid = tid >> 6;
  const int wm = wid >> 1, wn = wid & 1;
  const int lr = l & 15, lg = l >> 4;
  // XCD-bijective swizzle: nwg divisible by 8 for all grids used here.
  const int nbx = gridDim.x;
  const int nwg = nbx * gridDim.y;
  const int bid = blockIdx.x + nbx * blockIdx.y;
  const int swz = (bid & 7) * (nwg >> 3) + (bid >> 3);
  const int m0 = (swz / nbx) * 256, n0 = (swz % nbx) * 256;
  const int z = blockIdx.z;
  const int NT = Kc >> 6;

  A += (size_t)z * Kc;
  BT += (size_t)z * Kc;
  CB += (size_t)z * zoff;

  const int srow = tid >> 3;                    // 0..63 row within a slot
  const int scs = (tid & 7) ^ (srow & 7);       // pre-swizzled source chunk
  const size_t sgoff = (size_t)srow * Kstride + scs * 8;
  const int slds = wid * 512;                   // wave-uniform ushort offset

  const ushort_t* ga = A + (size_t)m0 * Kstride + sgoff;
  const ushort_t* gb = BT + (size_t)n0 * Kstride + sgoff;
  const size_t rs = (size_t)64 * Kstride;       // 64-row stride (elements)

  f32x4 acc[4][8] = {};

  ushort_t* Ab0 = lds;
  ushort_t* Bb0 = lds + 16384;
  ushort_t* Ab1 = lds + 32768;
  ushort_t* Bb1 = lds + 49152;

  // prologue: tile0 -> dbuf0, issue order A0,A1,B0,B2,A2,A3,B1,B3
  gload_lds16(ga, Ab0 + slds);
  gload_lds16(ga + rs, Ab0 + 4096 + slds);
  gload_lds16(gb, Bb0 + slds);
  gload_lds16(gb + 2 * rs, Bb0 + 8192 + slds);
  gload_lds16(ga + 2 * rs, Ab0 + 8192 + slds);
  gload_lds16(ga + 3 * rs, Ab0 + 12288 + slds);
  gload_lds16(gb + rs, Bb0 + 4096 + slds);
  gload_lds16(gb + 3 * rs, Bb0 + 12288 + slds);
  asm volatile("s_waitcnt vmcnt(2)" ::: "memory");
  __builtin_amdgcn_s_barrier();

  for (int kt = 0; kt < NT - 1; ++kt) {
    const int d = kt & 1;
    const ushort_t* as = (d ? Ab1 : Ab0) + wm * 4096;
    const ushort_t* bsA = (d ? Bb1 : Bb0) + (wn * 2) * 4096;
    ushort_t* nA = d ? Ab0 : Ab1;
    ushort_t* nB = d ? Bb0 : Bb1;
    g256_iter<0>(as, bsA, bsA + 4096, nA, nB, ga + (size_t)(kt + 1) * 64,
                 gb + (size_t)(kt + 1) * 64, rs, slds, lr, lg, acc);
  }
  {
    const int d = (NT - 1) & 1;
    const ushort_t* as = (d ? Ab1 : Ab0) + wm * 4096;
    const ushort_t* bsA = (d ? Bb1 : Bb0) + (wn * 2) * 4096;
    g256_iter<1>(as, bsA, bsA + 4096, nullptr, nullptr, nullptr, nullptr, rs,
                 slds, lr, lg, acc);
  }

  // epilogue
#pragma unroll
  for (int mi = 0; mi < 4; ++mi)
#pragma unroll
    for (int ci = 0; ci < 8; ++ci)
#pragma unroll
      for (int rr = 0; rr < 4; ++rr) {
        int m = m0 + wm * 64 + mi * 16 + lg * 4 + rr;
        int n = n0 + wn * 128 + ci * 16 + lr;
        size_t off = (size_t)m * N + n;
        float v = acc[mi][ci][rr];
        if constexpr (EPI == EPI_STOREB) {
          CB[off] = f2bf(v);
        } else {
          float gv = bf2f(GINB[off]);
          float s = gv / (1.f + __expf(-gv));
          CB[off] = f2bf(s * v);
        }
      }
}

// ---------------------------------------------------------------------------
// Post-QKV: sum 2 bf16 split-K partials + per-head RMSNorm (q,k) + RoPE.
// ---------------------------------------------------------------------------
__global__ __launch_bounds__(256) void k_qkv_post(const ushort_t* __restrict__ Q0,
                                                  const ushort_t* __restrict__ Q1,
                                                  const float* __restrict__ QNW,
                                                  const float* __restrict__ KNW,
                                                  const int* __restrict__ POS,
                                                  ushort_t* __restrict__ Qb,
                                                  ushort_t* __restrict__ Kb,
                                                  ushort_t* __restrict__ Vb) {
  int t = blockIdx.x;
  int tid = threadIdx.x;
  int w = tid >> 6, l = tid & 63;
  float pos = (float)POS[t];
  const ushort_t* base0 = Q0 + (size_t)t * 4096;
  const ushort_t* base1 = Q1 + (size_t)t * 4096;
  int i0 = 2 * (l & 31);
  const float K2 = 19.931568569324174f / 64.f;  // log2(1e6)/64
  float ang0 = pos * exp2f(-(float)i0 * K2);
  float ang1 = pos * exp2f(-(float)(i0 + 1) * K2);
  float cs0 = cosf(ang0), sn0 = sinf(ang0);
  float cs1 = cosf(ang1), sn1 = sinf(ang1);
#pragma unroll
  for (int si = 0; si < 8; ++si) {
    int slot = w + si * 4;
    ushort2 xa = *(const ushort2*)(base0 + slot * 128 + l * 2);
    ushort2 xb = *(const ushort2*)(base1 + slot * 128 + l * 2);
    float v0 = bf2f(xa.x) + bf2f(xb.x), v1 = bf2f(xa.y) + bf2f(xb.y);
    float ss = v0 * v0 + v1 * v1;
#pragma unroll
    for (int o = 1; o < 64; o <<= 1) ss += __shfl_xor(ss, o, 64);
    if (slot < 24) {
      float sc = rsqrtf(ss / 128.f + 1e-6f);
      const float* wn = (slot < 16) ? QNW : KNW;
      f32x2 wv = *(const f32x2*)(wn + l * 2);
      v0 = v0 * sc * wv.x;
      v1 = v1 * sc * wv.y;
      float p0 = __shfl_xor(v0, 32, 64);
      float p1 = __shfl_xor(v1, 32, 64);
      float r0 = (l < 32) ? -p0 : p0;
      float r1 = (l < 32) ? -p1 : p1;
      v0 = v0 * cs0 + r0 * sn0;
      v1 = v1 * cs1 + r1 * sn1;
    }
    ushort2 uv;
    uv.x = f2bf(v0);
    uv.y = f2bf(v1);
    ushort_t* dst;
    if (slot < 16)
      dst = Qb + (size_t)t * 2048 + slot * 128 + l * 2;
    else if (slot < 24)
      dst = Kb + (size_t)t * 1024 + (slot - 16) * 128 + l * 2;
    else
      dst = Vb + (size_t)t * 1024 + (slot - 24) * 128 + l * 2;
    *(ushort2*)dst = uv;
  }
}

// ---------------------------------------------------------------------------
// Flash attention, ragged causal mask.  1 wave per (16 q rows, KV head);
// both q-heads of the GQA group computed in-wave (shared K/V fragments).
// No __syncthreads: single-wave block, P-LDS roundtrip ordered by lgkmcnt.
// ---------------------------------------------------------------------------
__global__ __launch_bounds__(64) void k_flash(const ushort_t* __restrict__ Qb,
                                              const ushort_t* __restrict__ Kb,
                                              const ushort_t* __restrict__ VT,
                                              const int* __restrict__ SEG,
                                              ushort_t* __restrict__ Ob) {
  __shared__ ushort_t Pl[2][16 * 40];
  int l = threadIdx.x;
  int qt = blockIdx.x, kvh = blockIdx.y;
  int q0 = qt * 16;
  int lr = l & 15, lg = l >> 4;
  int h0 = kvh * 2;
  bf16x8 qf0[4], qf1[4];
  {
    const bf16x8* qv = (const bf16x8*)(Qb + (size_t)(q0 + lr) * 2048 + h0 * 128);
#pragma unroll
    for (int kk = 0; kk < 4; ++kk) {
      qf0[kk] = qv[kk * 4 + lg];
      qf1[kk] = qv[16 + kk * 4 + lg];
    }
  }
  int segq[4];
#pragma unroll
  for (int r = 0; r < 4; ++r) segq[r] = SEG[q0 + lg * 4 + r];
  int target = SEG[q0];
  int lo = 0, hi = q0;
  while (lo < hi) {
    int mid = (lo + hi) >> 1;
    if (SEG[mid] < target) lo = mid + 1; else hi = mid;
  }
  int s_start = lo & ~31;
  float mr[2][4], lrun[2][4];
  f32x4 acc[2][8] = {};
#pragma unroll
  for (int h = 0; h < 2; ++h)
#pragma unroll
    for (int r = 0; r < 4; ++r) { mr[h][r] = -1e30f; lrun[h][r] = 0.f; }
  const float scale = 0.08838834764831845f;  // 1/sqrt(128)
  for (int s0 = s_start; s0 < q0 + 16; s0 += 32) {
    int sa = s0 + lr, sb = s0 + 16 + lr;
    int sac = min(sa, T_SEQ - 1), sbc = min(sb, T_SEQ - 1);
    // V fragments issued early; consumed only after the P roundtrip.
    bf16x8 vfr[8];
    int sbase = min(s0 + lg * 8, T_SEQ - 8);
#pragma unroll
    for (int c = 0; c < 8; ++c)
      vfr[c] = *(const bf16x8*)(VT + (size_t)(kvh * 128 + c * 16 + lr) * T_SEQ + sbase);
    f32x4 SA0 = {}, SB0 = {}, SA1 = {}, SB1 = {};
    const bf16x8* ka = (const bf16x8*)(Kb + (size_t)sac * 1024 + kvh * 128);
    const bf16x8* kb_ = (const bf16x8*)(Kb + (size_t)sbc * 1024 + kvh * 128);
#pragma unroll
    for (int kk = 0; kk < 4; ++kk) {
      bf16x8 kaf = ka[kk * 4 + lg];
      bf16x8 kbf = kb_[kk * 4 + lg];
      SA0 = __builtin_amdgcn_mfma_f32_16x16x32_bf16(qf0[kk], kaf, SA0, 0, 0, 0);
      SB0 = __builtin_amdgcn_mfma_f32_16x16x32_bf16(qf0[kk], kbf, SB0, 0, 0, 0);
      SA1 = __builtin_amdgcn_mfma_f32_16x16x32_bf16(qf1[kk], kaf, SA1, 0, 0, 0);
      SB1 = __builtin_amdgcn_mfma_f32_16x16x32_bf16(qf1[kk], kbf, SB1, 0, 0, 0);
    }
    int sga = SEG[sac], sgb = SEG[sbc];
    bool mAv[4], mBv[4];
#pragma unroll
    for (int r = 0; r < 4; ++r) {
      int qrow = q0 + lg * 4 + r;
      mAv[r] = (sa <= qrow) && (sga == segq[r]);
      mBv[r] = (sb <= qrow) && (sgb == segq[r]);
    }
#pragma unroll
    for (int h = 0; h < 2; ++h) {
#pragma unroll
      for (int r = 0; r < 4; ++r) {
        float sva = (h ? SA1[r] : SA0[r]);
        float svb = (h ? SB1[r] : SB0[r]);
        float xa = mAv[r] ? sva * scale : -1e30f;
        float xb = mBv[r] ? svb * scale : -1e30f;
        float mx = fmaxf(xa, xb);
#pragma unroll
        for (int o = 1; o < 16; o <<= 1) mx = fmaxf(mx, __shfl_xor(mx, o, 64));
        float nm = fmaxf(mr[h][r], mx);
        float ea = __expf(xa - nm), eb = __expf(xb - nm);
        float rsum = ea + eb;
#pragma unroll
        for (int o = 1; o < 16; o <<= 1) rsum += __shfl_xor(rsum, o, 64);
        float al = __expf(mr[h][r] - nm);
        lrun[h][r] = lrun[h][r] * al + rsum;
        mr[h][r] = nm;
#pragma unroll
        for (int c = 0; c < 8; ++c) acc[h][c][r] *= al;
        Pl[h][(lg * 4 + r) * 40 + lr] = f2bf(ea);
        Pl[h][(lg * 4 + r) * 40 + 16 + lr] = f2bf(eb);
      }
    }
    // single-wave block: LDS ordering only (keeps global loads in flight)
    asm volatile("s_waitcnt lgkmcnt(0)" ::: "memory");
    bf16x8 pa0 = *(const bf16x8*)&Pl[0][lr * 40 + lg * 8];
    bf16x8 pa1 = *(const bf16x8*)&Pl[1][lr * 40 + lg * 8];
#pragma unroll
    for (int c = 0; c < 8; ++c) {
      acc[0][c] = __builtin_amdgcn_mfma_f32_16x16x32_bf16(pa0, vfr[c], acc[0][c], 0, 0, 0);
      acc[1][c] = __builtin_amdgcn_mfma_f32_16x16x32_bf16(pa1, vfr[c], acc[1][c], 0, 0, 0);
    }
  }
#pragma unroll
  for (int h = 0; h < 2; ++h)
#pragma unroll
    for (int c = 0; c < 8; ++c)
#pragma unroll
      for (int r = 0; r < 4; ++r) {
        float ov = acc[h][c][r] / lrun[h][r];
        Ob[(size_t)(q0 + lg * 4 + r) * 2048 + (h0 + h) * 128 + c * 16 + lr] = f2bf(ov);
      }
}

// ---------------------------------------------------------------------------
extern "C" void kernel_launch(void* const* d_in, const int* in_sizes, int n_in,
                              void* d_out, int out_size, void* d_ws, size_t ws_size,
                              hipStream_t stream) {
  const float* hidden = (const float*)d_in[0];
  const float* ln1 = (const float*)d_in[1];
  const float* ln2 = (const float*)d_in[2];
  const float* wq = (const float*)d_in[3];
  const float* wk = (const float*)d_in[4];
  const float* wv = (const float*)d_in[5];
  const float* wo = (const float*)d_in[6];
  const float* qnw = (const float*)d_in[7];
  const float* knw = (const float*)d_in[8];
  const float* wg = (const float*)d_in[9];
  const float* wu = (const float*)d_in[10];
  const float* wd = (const float*)d_in[11];
  const float* fnw = (const float*)d_in[12];
  const int* seg = (const int*)d_in[13];
  const int* pos = (const int*)d_in[14];
  float* out = (float*)d_out;

  char* ws = (char*)d_ws;
  size_t off = 0;
  auto alloc = [&](size_t bytes) {
    char* p = ws + off;
    off += (bytes + 255) & ~(size_t)255;
    return p;
  };
  ushort_t* wT = (ushort_t*)alloc((size_t)DFF * DMODEL * 2);       // rotating
  ushort_t* hbuf = (ushort_t*)alloc((size_t)T_SEQ * DMODEL * 2);
  ushort_t* qb = (ushort_t*)alloc((size_t)T_SEQ * 2048 * 2);
  ushort_t* kb = (ushort_t*)alloc((size_t)T_SEQ * 1024 * 2);
  ushort_t* vb = (ushort_t*)alloc((size_t)T_SEQ * 1024 * 2);
  ushort_t* vT = (ushort_t*)alloc((size_t)T_SEQ * 1024 * 2);
  ushort_t* ob = (ushort_t*)alloc((size_t)T_SEQ * 2048 * 2);
  ushort_t* qkvp = (ushort_t*)alloc((size_t)2 * T_SEQ * 4096 * 2); // bf16 partials
  ushort_t* pbuf = (ushort_t*)alloc((size_t)4 * T_SEQ * DMODEL * 2);
  ushort_t* gbufB = (ushort_t*)alloc((size_t)T_SEQ * DFF * 2);
  ushort_t* mbuf = (ushort_t*)alloc((size_t)T_SEQ * DFF * 2);
  (void)ws_size; (void)in_sizes; (void)n_in; (void)out_size;

  dim3 b256(256), b64(64), b512(512);
  // layer-0 input norm
  k_rmsnorm<1><<<T_SEQ, b256, 0, stream>>>(hidden, ln1, hbuf);

  for (int lyr = 0; lyr < 2; ++lyr) {
    const float* xsrc = (lyr == 0) ? hidden : out;

    const float* wql = wq + (size_t)lyr * DMODEL * 2048;
    const float* wkl = wk + (size_t)lyr * DMODEL * 1024;
    const float* wvl = wv + (size_t)lyr * DMODEL * 1024;
    k_transpose_bf16<float><<<dim3(32, 32), b256, 0, stream>>>(wql, wT, 2048, 2048);
    k_transpose_bf16<float><<<dim3(16, 32), b256, 0, stream>>>(wkl, wT + (size_t)2048 * 2048, 2048, 1024);
    k_transpose_bf16<float><<<dim3(16, 32), b256, 0, stream>>>(wvl, wT + (size_t)3072 * 2048, 2048, 1024);
    // QKV split-K=2 (Kc=1024): bf16 partials -> qkvp[z * 2048*4096]
    k_gemm256<EPI_STOREB><<<dim3(16, 8, 2), b512, 0, stream>>>(
        hbuf, wT, nullptr, qkvp, 4096, 2048, 1024, (size_t)2048 * 4096);
    k_qkv_post<<<T_SEQ, b256, 0, stream>>>(qkvp, qkvp + (size_t)2048 * 4096,
                                           qnw + (size_t)lyr * 128, knw + (size_t)lyr * 128,
                                           pos, qb, kb, vb);
    k_transpose_bf16<ushort_t><<<dim3(16, 32), b256, 0, stream>>>(vb, vT, 2048, 1024);
    k_flash<<<dim3(T_SEQ / 16, NKV), b64, 0, stream>>>(qb, kb, vT, seg, ob);

    const float* wol = wo + (size_t)lyr * 2048 * DMODEL;
    k_transpose_bf16<float><<<dim3(32, 32), b256, 0, stream>>>(wol, wT, 2048, 2048);
    // WO split-K=4 (Kc=512): bf16 partials, then fused residual+reduce+ln2
    k_gemm256<EPI_STOREB><<<dim3(8, 8, 4), b512, 0, stream>>>(
        ob, wT, nullptr, pbuf, 2048, 2048, 512, (size_t)2048 * 2048);
    k_redln<4, 1><<<T_SEQ, b512, 0, stream>>>(pbuf, xsrc,
                                              ln2 + (size_t)lyr * DMODEL, out, hbuf);

    const float* wgl = wg + (size_t)lyr * DMODEL * DFF;
    const float* wul = wu + (size_t)lyr * DMODEL * DFF;
    const float* wdl = wd + (size_t)lyr * DFF * DMODEL;
    k_transpose_bf16<float><<<dim3(128, 32), b256, 0, stream>>>(wgl, wT, 2048, 8192);
    k_gemm256<EPI_STOREB><<<dim3(32, 8, 1), b512, 0, stream>>>(
        hbuf, wT, nullptr, gbufB, 8192, 2048, 2048, 0);
    k_transpose_bf16<float><<<dim3(128, 32), b256, 0, stream>>>(wul, wT, 2048, 8192);
    k_gemm256<EPI_SILU><<<dim3(32, 8, 1), b512, 0, stream>>>(
        hbuf, wT, gbufB, mbuf, 8192, 2048, 2048, 0);
    k_transpose_bf16<float><<<dim3(32, 128), b256, 0, stream>>>(wdl, wT, 8192, 2048);
    // WD split-K=4 (Kc=2048): bf16 partials, fused residual+reduce(+next ln1)
    k_gemm256<EPI_STOREB><<<dim3(8, 8, 4), b512, 0, stream>>>(
        mbuf, wT, nullptr, pbuf, 2048, 8192, 2048, (size_t)2048 * 2048);
    if (lyr == 0) {
      k_redln<4, 1><<<T_SEQ, b512, 0, stream>>>(pbuf, out, ln1 + DMODEL, out, hbuf);
    } else {
      k_redln<4, 0><<<T_SEQ, b512, 0, stream>>>(pbuf, out, nullptr, out, nullptr);
    }
  }
  k_rmsnorm<0><<<T_SEQ, b256, 0, stream>>>(out, fnw, out);
}

// Round 11
// 830.932 us; speedup vs baseline: 1.2783x; 1.0499x over previous
//
#include <hip/hip_runtime.h>
#include <stdint.h>

#define T_SEQ 2048
#define DMODEL 2048
#define NH 16
#define NKV 8
#define DHEAD 128
#define DFF 8192

typedef float f32x4 __attribute__((ext_vector_type(4)));
typedef float f32x2 __attribute__((ext_vector_type(2)));
typedef __bf16 bf16x8 __attribute__((ext_vector_type(8)));
typedef unsigned short ushort_t;

typedef __attribute__((address_space(1))) void gvoid;
typedef __attribute__((address_space(3))) void lvoid;

__device__ inline unsigned short f2bf(float f) {
  unsigned int u = __float_as_uint(f);
  u += 0x7fffu + ((u >> 16) & 1u);
  return (unsigned short)(u >> 16);
}
__device__ inline float bf2f(unsigned short h) {
  return __uint_as_float(((unsigned int)h) << 16);
}

__device__ inline void gload_lds16(const void* g, void* l) {
  // 16B per lane; LDS dest is wave-uniform base + lane*16 (HW rule)
  __builtin_amdgcn_global_load_lds((gvoid*)g, (lvoid*)l, 16, 0, 0);
}

// ---------------------------------------------------------------------------
// Transpose + convert: in f32/bf16 [R][C] -> out bf16 [C][R].  Tile 64x64.
// rmode: 0 identity; 1 gate-interleave row=(n>>4)*32+(n&15); 2 up (+16).
// ---------------------------------------------------------------------------
template <typename TIN>
__global__ __launch_bounds__(256) void k_transpose_bf16(const TIN* __restrict__ in,
                                                        ushort_t* __restrict__ out,
                                                        int R, int C, int rmode) {
  __shared__ float tile[64 * 72];
  int tid = threadIdx.x;
  int r0 = blockIdx.y * 64, c0 = blockIdx.x * 64;
  int rl = tid >> 4;   // 0..15
  int cc = tid & 15;   // 16B col chunk
#pragma unroll
  for (int i = 0; i < 4; ++i) {
    int row = rl + i * 16;
    const TIN* src = in + (size_t)(r0 + row) * C + c0 + cc * 4;
    float v0, v1, v2, v3;
    if constexpr (sizeof(TIN) == 4) {
      f32x4 v = *(const f32x4*)src;
      v0 = v.x; v1 = v.y; v2 = v.z; v3 = v.w;
    } else {
      ushort4 v = *(const ushort4*)src;
      v0 = bf2f(v.x); v1 = bf2f(v.y); v2 = bf2f(v.z); v3 = bf2f(v.w);
    }
    int chunk = cc ^ (row & 15);
    f32x4 t = {v0, v1, v2, v3};
    *(f32x4*)&tile[row * 72 + chunk * 4] = t;
  }
  __syncthreads();
#pragma unroll
  for (int i = 0; i < 4; ++i) {
    int nrow = rl + i * 16;   // output row local = input col
    int k4 = cc * 4;          // output col local base = input row
    ushort4 o;
    {
      int k = k4 + 0;
      o.x = f2bf(tile[k * 72 + (((nrow >> 2) ^ (k & 15)) << 2) + (nrow & 3)]);
      k = k4 + 1;
      o.y = f2bf(tile[k * 72 + (((nrow >> 2) ^ (k & 15)) << 2) + (nrow & 3)]);
      k = k4 + 2;
      o.z = f2bf(tile[k * 72 + (((nrow >> 2) ^ (k & 15)) << 2) + (nrow & 3)]);
      k = k4 + 3;
      o.w = f2bf(tile[k * 72 + (((nrow >> 2) ^ (k & 15)) << 2) + (nrow & 3)]);
    }
    int n = c0 + nrow;
    int orow = n;
    if (rmode == 1) orow = ((n >> 4) << 5) + (n & 15);
    else if (rmode == 2) orow = ((n >> 4) << 5) + 16 + (n & 15);
    *(ushort4*)(out + (size_t)orow * R + r0 + k4) = o;
  }
}

// ---------------------------------------------------------------------------
// RMSNorm over D=2048, one block (256 thr) per row.
// ---------------------------------------------------------------------------
template <int BF16OUT>
__global__ __launch_bounds__(256) void k_rmsnorm(const float* __restrict__ X,
                                                 const float* __restrict__ W,
                                                 void* __restrict__ OUT) {
  int row = blockIdx.x, tid = threadIdx.x;
  const float* xr = X + (size_t)row * DMODEL;
  f32x4 x0 = *(const f32x4*)(xr + tid * 4);
  f32x4 x1 = *(const f32x4*)(xr + 1024 + tid * 4);
  float ss = x0.x * x0.x + x0.y * x0.y + x0.z * x0.z + x0.w * x0.w +
             x1.x * x1.x + x1.y * x1.y + x1.z * x1.z + x1.w * x1.w;
#pragma unroll
  for (int o = 1; o < 64; o <<= 1) ss += __shfl_xor(ss, o, 64);
  __shared__ float red[4];
  int w = tid >> 6;
  if ((tid & 63) == 0) red[w] = ss;
  __syncthreads();
  float tot = red[0] + red[1] + red[2] + red[3];
  float sc = rsqrtf(tot / (float)DMODEL + 1e-6f);
  f32x4 w0 = *(const f32x4*)(W + tid * 4);
  f32x4 w1 = *(const f32x4*)(W + 1024 + tid * 4);
  if constexpr (BF16OUT) {
    ushort_t* o = (ushort_t*)OUT + (size_t)row * DMODEL;
    ushort4 a, b;
    a.x = f2bf(x0.x * sc * w0.x); a.y = f2bf(x0.y * sc * w0.y);
    a.z = f2bf(x0.z * sc * w0.z); a.w = f2bf(x0.w * sc * w0.w);
    b.x = f2bf(x1.x * sc * w1.x); b.y = f2bf(x1.y * sc * w1.y);
    b.z = f2bf(x1.z * sc * w1.z); b.w = f2bf(x1.w * sc * w1.w);
    *(ushort4*)(o + tid * 4) = a;
    *(ushort4*)(o + 1024 + tid * 4) = b;
  } else {
    float* o = (float*)OUT + (size_t)row * DMODEL;
    f32x4 a = {x0.x * sc * w0.x, x0.y * sc * w0.y, x0.z * sc * w0.z, x0.w * sc * w0.w};
    f32x4 b = {x1.x * sc * w1.x, x1.y * sc * w1.y, x1.z * sc * w1.z, x1.w * sc * w1.w};
    *(f32x4*)(o + tid * 4) = a;
    *(f32x4*)(o + 1024 + tid * 4) = b;
  }
}

// ---------------------------------------------------------------------------
// Fused: OUT[row] = RES[row] + sum_z P_bf16[z][row]; optionally
// HB[row] = rmsnorm(OUT[row]) * W  (bf16).  One block (512 thr) per row.
// ---------------------------------------------------------------------------
template <int NZ, int WRITEH>
__global__ __launch_bounds__(512) void k_redln(const ushort_t* __restrict__ P,
                                               const float* __restrict__ RES,
                                               const float* __restrict__ W,
                                               float* __restrict__ OUT,
                                               ushort_t* __restrict__ HB) {
  int row = blockIdx.x, tid = threadIdx.x;
  size_t base = (size_t)row * DMODEL + tid * 4;
  f32x4 v = *(const f32x4*)(RES + base);
#pragma unroll
  for (int z = 0; z < NZ; ++z) {
    ushort4 t = *(const ushort4*)(P + (size_t)z * T_SEQ * DMODEL + base);
    v.x += bf2f(t.x); v.y += bf2f(t.y); v.z += bf2f(t.z); v.w += bf2f(t.w);
  }
  *(f32x4*)(OUT + base) = v;
  if constexpr (WRITEH) {
    float ss = v.x * v.x + v.y * v.y + v.z * v.z + v.w * v.w;
#pragma unroll
    for (int o = 1; o < 64; o <<= 1) ss += __shfl_xor(ss, o, 64);
    __shared__ float red[8];
    if ((tid & 63) == 0) red[tid >> 6] = ss;
    __syncthreads();
    float tot = 0.f;
#pragma unroll
    for (int i = 0; i < 8; ++i) tot += red[i];
    float sc = rsqrtf(tot / (float)DMODEL + 1e-6f);
    f32x4 wv = *(const f32x4*)(W + tid * 4);
    ushort4 h;
    h.x = f2bf(v.x * sc * wv.x); h.y = f2bf(v.y * sc * wv.y);
    h.z = f2bf(v.z * sc * wv.z); h.w = f2bf(v.w * sc * wv.w);
    *(ushort4*)(HB + base) = h;
  }
}

// ---------------------------------------------------------------------------
// 256x256 8-phase GEMM (T2 swizzle + T3/T4 counted vmcnt + T5 setprio).
// 8 waves 4Mx2N, BK=64, LDS 128KB double-buffered, 8 slots/tile of 64 rows.
// Stage issue (for t+1): P0: A0,A1,B0,B2   P1: A2,A3,B1,B3.
// Waits: vmcnt(8) @P1 (prev tile's B1,B3), vmcnt(2) @P3 (this tile's P0/P1).
// Barriers: 5/K-tile — trailing barrier kept only at P3 (publishes completed
// reads of outgoing buffer); P0-P2 trailing barriers dropped (waves may drift
// within a tile; rendezvous counts stay matched).
// Square-chunk XCD swizzle: each XCD owns a 4m x cn tile chunk.
// EPI: 3 store bf16 (partials), 5 fused SiLU-GLU (interleaved gate/up cols).
// ---------------------------------------------------------------------------
#define EPI_STOREB 3
#define EPI_GLU 5

#define LOAD_B256(bs, rbase)                                                   \
  {                                                                            \
    _Pragma("unroll") for (int ks = 0; ks < 2; ++ks)                           \
        _Pragma("unroll") for (int ni = 0; ni < 2; ++ni)                       \
            bfr[ks][ni] = *(const bf16x8*)((bs) +                              \
                (((rbase) + ni * 16 + lr) << 6) +                              \
                ((((ks << 2) + lg) ^ (lr & 7)) << 3));                         \
  }

#define MFMA_Q256(q)                                                           \
  {                                                                            \
    _Pragma("unroll") for (int ks = 0; ks < 2; ++ks)                           \
        _Pragma("unroll") for (int mi = 0; mi < 4; ++mi)                       \
            _Pragma("unroll") for (int ni = 0; ni < 2; ++ni)                   \
                acc[mi][(q) * 2 + ni] =                                        \
                    __builtin_amdgcn_mfma_f32_16x16x32_bf16(                   \
                        af[ks][mi], bfr[ks][ni], acc[mi][(q) * 2 + ni], 0, 0, 0); \
  }

template <int LAST>
__device__ __forceinline__ void g256_iter(
    const ushort_t* __restrict__ as, const ushort_t* __restrict__ bsA,
    const ushort_t* __restrict__ bsB, ushort_t* __restrict__ nA,
    ushort_t* __restrict__ nB, const ushort_t* __restrict__ an,
    const ushort_t* __restrict__ bn, size_t rs, int slds, int lr, int lg,
    f32x4 (&acc)[4][8]) {
  bf16x8 af[2][4], bfr[2][2];
  // ---- P0: ds-read A frags + B(slot lo, rows 0-31); issue A0,A1,B0,B2 ----
#pragma unroll
  for (int ks = 0; ks < 2; ++ks)
#pragma unroll
    for (int mi = 0; mi < 4; ++mi)
      af[ks][mi] = *(const bf16x8*)(as + ((mi * 16 + lr) << 6) +
                                    ((((ks << 2) + lg) ^ (lr & 7)) << 3));
  LOAD_B256(bsA, 0);
  if constexpr (!LAST) {
    gload_lds16(an, nA + slds);
    gload_lds16(an + rs, nA + 4096 + slds);
    gload_lds16(bn, nB + slds);
    gload_lds16(bn + 2 * rs, nB + 8192 + slds);
  }
  __builtin_amdgcn_s_barrier();
  asm volatile("s_waitcnt lgkmcnt(0)" ::: "memory");
  __builtin_amdgcn_sched_barrier(0);
  __builtin_amdgcn_s_setprio(1);
  MFMA_Q256(0);
  __builtin_amdgcn_s_setprio(0);
  // ---- P1: issue A2,A3,B1,B3; wait for PREV tile's B1,B3 ----
  LOAD_B256(bsA, 32);
  if constexpr (!LAST) {
    gload_lds16(an + 2 * rs, nA + 8192 + slds);
    gload_lds16(an + 3 * rs, nA + 12288 + slds);
    gload_lds16(bn + rs, nB + 4096 + slds);
    gload_lds16(bn + 3 * rs, nB + 12288 + slds);
    asm volatile("s_waitcnt vmcnt(8)" ::: "memory");
  } else {
    asm volatile("s_waitcnt vmcnt(0)" ::: "memory");
  }
  __builtin_amdgcn_s_barrier();
  asm volatile("s_waitcnt lgkmcnt(0)" ::: "memory");
  __builtin_amdgcn_sched_barrier(0);
  __builtin_amdgcn_s_setprio(1);
  MFMA_Q256(1);
  __builtin_amdgcn_s_setprio(0);
  // ---- P2 ----
  LOAD_B256(bsB, 0);
  __builtin_amdgcn_s_barrier();
  asm volatile("s_waitcnt lgkmcnt(0)" ::: "memory");
  __builtin_amdgcn_sched_barrier(0);
  __builtin_amdgcn_s_setprio(1);
  MFMA_Q256(2);
  __builtin_amdgcn_s_setprio(0);
  // ---- P3: wait for this tile's A0-3,B0,B2 (issued 2-3 phases ago) ----
  LOAD_B256(bsB, 32);
  if constexpr (!LAST) {
    asm volatile("s_waitcnt vmcnt(2)" ::: "memory");
  }
  __builtin_amdgcn_s_barrier();
  asm volatile("s_waitcnt lgkmcnt(0)" ::: "memory");
  __builtin_amdgcn_sched_barrier(0);
  __builtin_amdgcn_s_setprio(1);
  MFMA_Q256(3);
  __builtin_amdgcn_s_setprio(0);
  __builtin_amdgcn_s_barrier();   // tile-boundary: publish completed reads
}

template <int EPI>
__global__ __launch_bounds__(512, 2) void k_gemm256(
    const ushort_t* __restrict__ A, const ushort_t* __restrict__ BT,
    ushort_t* __restrict__ CB, int N, int Kstride, int Kc, size_t zoff) {
  __shared__ ushort_t lds[65536];  // 128 KiB
  const int tid = threadIdx.x;
  const int l = tid & 63, wid = tid >> 6;
  const int wm = wid >> 1, wn = wid & 1;
  const int lr = l & 15, lg = l >> 4;
  // Square-chunk XCD swizzle: XCD x (= bid%8) owns a cm x cn tile chunk.
  // Requires nwg%32==0 (all grids here satisfy: 128/64/512 per z-slice).
  const int gx = gridDim.x;
  const int nwg = gx * gridDim.y;
  const int bid = blockIdx.x + gx * blockIdx.y;
  const int chunk = nwg >> 3;
  const int x = bid & 7;
  const int local = bid >> 3;
  const int cn = chunk >> 2;           // cm = 4
  const int ncx = gx / cn;
  const int m0 = ((x / ncx) * 4 + local / cn) * 256;
  const int n0 = ((x % ncx) * cn + local % cn) * 256;
  const int z = blockIdx.z;
  const int NT = Kc >> 6;

  A += (size_t)z * Kc;
  BT += (size_t)z * Kc;
  CB += (size_t)z * zoff;

  const int srow = tid >> 3;                    // 0..63 row within a slot
  const int scs = (tid & 7) ^ (srow & 7);       // pre-swizzled source chunk
  const size_t sgoff = (size_t)srow * Kstride + scs * 8;
  const int slds = wid * 512;                   // wave-uniform ushort offset

  const ushort_t* ga = A + (size_t)m0 * Kstride + sgoff;
  const ushort_t* gb = BT + (size_t)n0 * Kstride + sgoff;
  const size_t rs = (size_t)64 * Kstride;       // 64-row stride (elements)

  f32x4 acc[4][8] = {};

  ushort_t* Ab0 = lds;
  ushort_t* Bb0 = lds + 16384;
  ushort_t* Ab1 = lds + 32768;
  ushort_t* Bb1 = lds + 49152;

  // prologue: tile0 -> dbuf0, issue order A0,A1,B0,B2,A2,A3,B1,B3
  gload_lds16(ga, Ab0 + slds);
  gload_lds16(ga + rs, Ab0 + 4096 + slds);
  gload_lds16(gb, Bb0 + slds);
  gload_lds16(gb + 2 * rs, Bb0 + 8192 + slds);
  gload_lds16(ga + 2 * rs, Ab0 + 8192 + slds);
  gload_lds16(ga + 3 * rs, Ab0 + 12288 + slds);
  gload_lds16(gb + rs, Bb0 + 4096 + slds);
  gload_lds16(gb + 3 * rs, Bb0 + 12288 + slds);
  asm volatile("s_waitcnt vmcnt(2)" ::: "memory");
  __builtin_amdgcn_s_barrier();

  for (int kt = 0; kt < NT - 1; ++kt) {
    const int d = kt & 1;
    const ushort_t* as = (d ? Ab1 : Ab0) + wm * 4096;
    const ushort_t* bsA = (d ? Bb1 : Bb0) + (wn * 2) * 4096;
    ushort_t* nA = d ? Ab0 : Ab1;
    ushort_t* nB = d ? Bb0 : Bb1;
    g256_iter<0>(as, bsA, bsA + 4096, nA, nB, ga + (size_t)(kt + 1) * 64,
                 gb + (size_t)(kt + 1) * 64, rs, slds, lr, lg, acc);
  }
  {
    const int d = (NT - 1) & 1;
    const ushort_t* as = (d ? Ab1 : Ab0) + wm * 4096;
    const ushort_t* bsA = (d ? Bb1 : Bb0) + (wn * 2) * 4096;
    g256_iter<1>(as, bsA, bsA + 4096, nullptr, nullptr, nullptr, nullptr, rs,
                 slds, lr, lg, acc);
  }

  // epilogue
  if constexpr (EPI == EPI_GLU) {
    // Interleaved gate/up: even ci = gate, odd ci = up (same lane, same col).
#pragma unroll
    for (int mi = 0; mi < 4; ++mi)
#pragma unroll
      for (int ci = 0; ci < 8; ci += 2)
#pragma unroll
        for (int rr = 0; rr < 4; ++rr) {
          int m = m0 + wm * 64 + mi * 16 + lg * 4 + rr;
          int nblk = n0 + wn * 128 + ci * 16;
          int col = ((nblk >> 5) << 4) + lr;
          float gv = acc[mi][ci][rr];
          float uv = acc[mi][ci + 1][rr];
          float s = gv / (1.f + __expf(-gv));
          CB[(size_t)m * 8192 + col] = f2bf(s * uv);
        }
  } else {
#pragma unroll
    for (int mi = 0; mi < 4; ++mi)
#pragma unroll
      for (int ci = 0; ci < 8; ++ci)
#pragma unroll
        for (int rr = 0; rr < 4; ++rr) {
          int m = m0 + wm * 64 + mi * 16 + lg * 4 + rr;
          int n = n0 + wn * 128 + ci * 16 + lr;
          CB[(size_t)m * N + n] = f2bf(acc[mi][ci][rr]);
        }
  }
}

// ---------------------------------------------------------------------------
// Post-QKV: sum 2 bf16 split-K partials + per-head RMSNorm (q,k) + RoPE.
// ---------------------------------------------------------------------------
__global__ __launch_bounds__(256) void k_qkv_post(const ushort_t* __restrict__ Q0,
                                                  const ushort_t* __restrict__ Q1,
                                                  const float* __restrict__ QNW,
                                                  const float* __restrict__ KNW,
                                                  const int* __restrict__ POS,
                                                  ushort_t* __restrict__ Qb,
                                                  ushort_t* __restrict__ Kb,
                                                  ushort_t* __restrict__ Vb) {
  int t = blockIdx.x;
  int tid = threadIdx.x;
  int w = tid >> 6, l = tid & 63;
  float pos = (float)POS[t];
  const ushort_t* base0 = Q0 + (size_t)t * 4096;
  const ushort_t* base1 = Q1 + (size_t)t * 4096;
  int i0 = 2 * (l & 31);
  const float K2 = 19.931568569324174f / 64.f;  // log2(1e6)/64
  float ang0 = pos * exp2f(-(float)i0 * K2);
  float ang1 = pos * exp2f(-(float)(i0 + 1) * K2);
  float cs0 = cosf(ang0), sn0 = sinf(ang0);
  float cs1 = cosf(ang1), sn1 = sinf(ang1);
#pragma unroll
  for (int si = 0; si < 8; ++si) {
    int slot = w + si * 4;
    ushort2 xa = *(const ushort2*)(base0 + slot * 128 + l * 2);
    ushort2 xb = *(const ushort2*)(base1 + slot * 128 + l * 2);
    float v0 = bf2f(xa.x) + bf2f(xb.x), v1 = bf2f(xa.y) + bf2f(xb.y);
    float ss = v0 * v0 + v1 * v1;
#pragma unroll
    for (int o = 1; o < 64; o <<= 1) ss += __shfl_xor(ss, o, 64);
    if (slot < 24) {
      float sc = rsqrtf(ss / 128.f + 1e-6f);
      const float* wn = (slot < 16) ? QNW : KNW;
      f32x2 wv = *(const f32x2*)(wn + l * 2);
      v0 = v0 * sc * wv.x;
      v1 = v1 * sc * wv.y;
      float p0 = __shfl_xor(v0, 32, 64);
      float p1 = __shfl_xor(v1, 32, 64);
      float r0 = (l < 32) ? -p0 : p0;
      float r1 = (l < 32) ? -p1 : p1;
      v0 = v0 * cs0 + r0 * sn0;
      v1 = v1 * cs1 + r1 * sn1;
    }
    ushort2 uv;
    uv.x = f2bf(v0);
    uv.y = f2bf(v1);
    ushort_t* dst;
    if (slot < 16)
      dst = Qb + (size_t)t * 2048 + slot * 128 + l * 2;
    else if (slot < 24)
      dst = Kb + (size_t)t * 1024 + (slot - 16) * 128 + l * 2;
    else
      dst = Vb + (size_t)t * 1024 + (slot - 24) * 128 + l * 2;
    *(ushort2*)dst = uv;
  }
}

// ---------------------------------------------------------------------------
// Flash attention, ragged causal mask.  1 wave per (16 q rows, KV head);
// both q-heads of the GQA group computed in-wave (shared K/V fragments).
// No __syncthreads: single-wave block, P-LDS roundtrip ordered by lgkmcnt.
// ---------------------------------------------------------------------------
__global__ __launch_bounds__(64) void k_flash(const ushort_t* __restrict__ Qb,
                                              const ushort_t* __restrict__ Kb,
                                              const ushort_t* __restrict__ VT,
                                              const int* __restrict__ SEG,
                                              ushort_t* __restrict__ Ob) {
  __shared__ ushort_t Pl[2][16 * 40];
  int l = threadIdx.x;
  int qt = blockIdx.x, kvh = blockIdx.y;
  int q0 = qt * 16;
  int lr = l & 15, lg = l >> 4;
  int h0 = kvh * 2;
  bf16x8 qf0[4], qf1[4];
  {
    const bf16x8* qv = (const bf16x8*)(Qb + (size_t)(q0 + lr) * 2048 + h0 * 128);
#pragma unroll
    for (int kk = 0; kk < 4; ++kk) {
      qf0[kk] = qv[kk * 4 + lg];
      qf1[kk] = qv[16 + kk * 4 + lg];
    }
  }
  int segq[4];
#pragma unroll
  for (int r = 0; r < 4; ++r) segq[r] = SEG[q0 + lg * 4 + r];
  int target = SEG[q0];
  int lo = 0, hi = q0;
  while (lo < hi) {
    int mid = (lo + hi) >> 1;
    if (SEG[mid] < target) lo = mid + 1; else hi = mid;
  }
  int s_start = lo & ~31;
  float mr[2][4], lrun[2][4];
  f32x4 acc[2][8] = {};
#pragma unroll
  for (int h = 0; h < 2; ++h)
#pragma unroll
    for (int r = 0; r < 4; ++r) { mr[h][r] = -1e30f; lrun[h][r] = 0.f; }
  const float scale = 0.08838834764831845f;  // 1/sqrt(128)
  for (int s0 = s_start; s0 < q0 + 16; s0 += 32) {
    int sa = s0 + lr, sb = s0 + 16 + lr;
    int sac = min(sa, T_SEQ - 1), sbc = min(sb, T_SEQ - 1);
    // V fragments issued early; consumed only after the P roundtrip.
    bf16x8 vfr[8];
    int sbase = min(s0 + lg * 8, T_SEQ - 8);
#pragma unroll
    for (int c = 0; c < 8; ++c)
      vfr[c] = *(const bf16x8*)(VT + (size_t)(kvh * 128 + c * 16 + lr) * T_SEQ + sbase);
    f32x4 SA0 = {}, SB0 = {}, SA1 = {}, SB1 = {};
    const bf16x8* ka = (const bf16x8*)(Kb + (size_t)sac * 1024 + kvh * 128);
    const bf16x8* kb_ = (const bf16x8*)(Kb + (size_t)sbc * 1024 + kvh * 128);
#pragma unroll
    for (int kk = 0; kk < 4; ++kk) {
      bf16x8 kaf = ka[kk * 4 + lg];
      bf16x8 kbf = kb_[kk * 4 + lg];
      SA0 = __builtin_amdgcn_mfma_f32_16x16x32_bf16(qf0[kk], kaf, SA0, 0, 0, 0);
      SB0 = __builtin_amdgcn_mfma_f32_16x16x32_bf16(qf0[kk], kbf, SB0, 0, 0, 0);
      SA1 = __builtin_amdgcn_mfma_f32_16x16x32_bf16(qf1[kk], kaf, SA1, 0, 0, 0);
      SB1 = __builtin_amdgcn_mfma_f32_16x16x32_bf16(qf1[kk], kbf, SB1, 0, 0, 0);
    }
    int sga = SEG[sac], sgb = SEG[sbc];
    bool mAv[4], mBv[4];
#pragma unroll
    for (int r = 0; r < 4; ++r) {
      int qrow = q0 + lg * 4 + r;
      mAv[r] = (sa <= qrow) && (sga == segq[r]);
      mBv[r] = (sb <= qrow) && (sgb == segq[r]);
    }
#pragma unroll
    for (int h = 0; h < 2; ++h) {
#pragma unroll
      for (int r = 0; r < 4; ++r) {
        float sva = (h ? SA1[r] : SA0[r]);
        float svb = (h ? SB1[r] : SB0[r]);
        float xa = mAv[r] ? sva * scale : -1e30f;
        float xb = mBv[r] ? svb * scale : -1e30f;
        float mx = fmaxf(xa, xb);
#pragma unroll
        for (int o = 1; o < 16; o <<= 1) mx = fmaxf(mx, __shfl_xor(mx, o, 64));
        float nm = fmaxf(mr[h][r], mx);
        float ea = __expf(xa - nm), eb = __expf(xb - nm);
        float rsum = ea + eb;
#pragma unroll
        for (int o = 1; o < 16; o <<= 1) rsum += __shfl_xor(rsum, o, 64);
        float al = __expf(mr[h][r] - nm);
        lrun[h][r] = lrun[h][r] * al + rsum;
        mr[h][r] = nm;
#pragma unroll
        for (int c = 0; c < 8; ++c) acc[h][c][r] *= al;
        Pl[h][(lg * 4 + r) * 40 + lr] = f2bf(ea);
        Pl[h][(lg * 4 + r) * 40 + 16 + lr] = f2bf(eb);
      }
    }
    // single-wave block: LDS ordering only (keeps global loads in flight)
    asm volatile("s_waitcnt lgkmcnt(0)" ::: "memory");
    bf16x8 pa0 = *(const bf16x8*)&Pl[0][lr * 40 + lg * 8];
    bf16x8 pa1 = *(const bf16x8*)&Pl[1][lr * 40 + lg * 8];
#pragma unroll
    for (int c = 0; c < 8; ++c) {
      acc[0][c] = __builtin_amdgcn_mfma_f32_16x16x32_bf16(pa0, vfr[c], acc[0][c], 0, 0, 0);
      acc[1][c] = __builtin_amdgcn_mfma_f32_16x16x32_bf16(pa1, vfr[c], acc[1][c], 0, 0, 0);
    }
  }
#pragma unroll
  for (int h = 0; h < 2; ++h)
#pragma unroll
    for (int c = 0; c < 8; ++c)
#pragma unroll
      for (int r = 0; r < 4; ++r) {
        float ov = acc[h][c][r] / lrun[h][r];
        Ob[(size_t)(q0 + lg * 4 + r) * 2048 + (h0 + h) * 128 + c * 16 + lr] = f2bf(ov);
      }
}

// ---------------------------------------------------------------------------
extern "C" void kernel_launch(void* const* d_in, const int* in_sizes, int n_in,
                              void* d_out, int out_size, void* d_ws, size_t ws_size,
                              hipStream_t stream) {
  const float* hidden = (const float*)d_in[0];
  const float* ln1 = (const float*)d_in[1];
  const float* ln2 = (const float*)d_in[2];
  const float* wq = (const float*)d_in[3];
  const float* wk = (const float*)d_in[4];
  const float* wv = (const float*)d_in[5];
  const float* wo = (const float*)d_in[6];
  const float* qnw = (const float*)d_in[7];
  const float* knw = (const float*)d_in[8];
  const float* wg = (const float*)d_in[9];
  const float* wu = (const float*)d_in[10];
  const float* wd = (const float*)d_in[11];
  const float* fnw = (const float*)d_in[12];
  const int* seg = (const int*)d_in[13];
  const int* pos = (const int*)d_in[14];
  float* out = (float*)d_out;

  char* ws = (char*)d_ws;
  size_t off = 0;
  auto alloc = [&](size_t bytes) {
    char* p = ws + off;
    off += (bytes + 255) & ~(size_t)255;
    return p;
  };
  ushort_t* wT = (ushort_t*)alloc((size_t)2 * DFF * DMODEL * 2);   // 67MB (fused gate/up)
  ushort_t* hbuf = (ushort_t*)alloc((size_t)T_SEQ * DMODEL * 2);
  ushort_t* qb = (ushort_t*)alloc((size_t)T_SEQ * 2048 * 2);
  ushort_t* kb = (ushort_t*)alloc((size_t)T_SEQ * 1024 * 2);
  ushort_t* vb = (ushort_t*)alloc((size_t)T_SEQ * 1024 * 2);
  ushort_t* vT = (ushort_t*)alloc((size_t)T_SEQ * 1024 * 2);
  ushort_t* ob = (ushort_t*)alloc((size_t)T_SEQ * 2048 * 2);
  ushort_t* qkvp = (ushort_t*)alloc((size_t)2 * T_SEQ * 4096 * 2); // bf16 partials
  ushort_t* pbuf = (ushort_t*)alloc((size_t)4 * T_SEQ * DMODEL * 2);
  ushort_t* mbuf = (ushort_t*)alloc((size_t)T_SEQ * DFF * 2);
  (void)ws_size; (void)in_sizes; (void)n_in; (void)out_size;

  dim3 b256(256), b64(64), b512(512);
  // layer-0 input norm
  k_rmsnorm<1><<<T_SEQ, b256, 0, stream>>>(hidden, ln1, hbuf);

  for (int lyr = 0; lyr < 2; ++lyr) {
    const float* xsrc = (lyr == 0) ? hidden : out;

    const float* wql = wq + (size_t)lyr * DMODEL * 2048;
    const float* wkl = wk + (size_t)lyr * DMODEL * 1024;
    const float* wvl = wv + (size_t)lyr * DMODEL * 1024;
    k_transpose_bf16<float><<<dim3(32, 32), b256, 0, stream>>>(wql, wT, 2048, 2048, 0);
    k_transpose_bf16<float><<<dim3(16, 32), b256, 0, stream>>>(wkl, wT + (size_t)2048 * 2048, 2048, 1024, 0);
    k_transpose_bf16<float><<<dim3(16, 32), b256, 0, stream>>>(wvl, wT + (size_t)3072 * 2048, 2048, 1024, 0);
    // QKV split-K=2 (Kc=1024): bf16 partials -> qkvp[z * 2048*4096]
    k_gemm256<EPI_STOREB><<<dim3(16, 8, 2), b512, 0, stream>>>(
        hbuf, wT, qkvp, 4096, 2048, 1024, (size_t)2048 * 4096);
    k_qkv_post<<<T_SEQ, b256, 0, stream>>>(qkvp, qkvp + (size_t)2048 * 4096,
                                           qnw + (size_t)lyr * 128, knw + (size_t)lyr * 128,
                                           pos, qb, kb, vb);
    k_transpose_bf16<ushort_t><<<dim3(16, 32), b256, 0, stream>>>(vb, vT, 2048, 1024, 0);
    k_flash<<<dim3(T_SEQ / 16, NKV), b64, 0, stream>>>(qb, kb, vT, seg, ob);

    const float* wol = wo + (size_t)lyr * 2048 * DMODEL;
    k_transpose_bf16<float><<<dim3(32, 32), b256, 0, stream>>>(wol, wT, 2048, 2048, 0);
    // WO split-K=4 (Kc=512): bf16 partials, then fused residual+reduce+ln2
    k_gemm256<EPI_STOREB><<<dim3(8, 8, 4), b512, 0, stream>>>(
        ob, wT, pbuf, 2048, 2048, 512, (size_t)2048 * 2048);
    k_redln<4, 1><<<T_SEQ, b512, 0, stream>>>(pbuf, xsrc,
                                              ln2 + (size_t)lyr * DMODEL, out, hbuf);

    const float* wgl = wg + (size_t)lyr * DMODEL * DFF;
    const float* wul = wu + (size_t)lyr * DMODEL * DFF;
    const float* wdl = wd + (size_t)lyr * DFF * DMODEL;
    // Fused gate+up: interleaved transpose into wT [16384][2048], one GEMM
    // with in-register SiLU-GLU epilogue -> mbuf bf16 [2048][8192].
    k_transpose_bf16<float><<<dim3(128, 32), b256, 0, stream>>>(wgl, wT, 2048, 8192, 1);
    k_transpose_bf16<float><<<dim3(128, 32), b256, 0, stream>>>(wul, wT, 2048, 8192, 2);
    k_gemm256<EPI_GLU><<<dim3(64, 8, 1), b512, 0, stream>>>(
        hbuf, wT, mbuf, 16384, 2048, 2048, 0);
    k_transpose_bf16<float><<<dim3(32, 128), b256, 0, stream>>>(wdl, wT, 8192, 2048, 0);
    // WD split-K=4 (Kc=2048): bf16 partials, fused residual+reduce(+next ln1)
    k_gemm256<EPI_STOREB><<<dim3(8, 8, 4), b512, 0, stream>>>(
        mbuf, wT, pbuf, 2048, 8192, 2048, (size_t)2048 * 2048);
    if (lyr == 0) {
      k_redln<4, 1><<<T_SEQ, b512, 0, stream>>>(pbuf, out, ln1 + DMODEL, out, hbuf);
    } else {
      k_redln<4, 0><<<T_SEQ, b512, 0, stream>>>(pbuf, out, nullptr, out, nullptr);
    }
  }
  k_rmsnorm<0><<<T_SEQ, b256, 0, stream>>>(out, fnw, out);
}

// Round 12
// 826.798 us; speedup vs baseline: 1.2847x; 1.0050x over previous
//
#include <hip/hip_runtime.h>
#include <stdint.h>

#define T_SEQ 2048
#define DMODEL 2048
#define NH 16
#define NKV 8
#define DHEAD 128
#define DFF 8192

typedef float f32x4 __attribute__((ext_vector_type(4)));
typedef float f32x2 __attribute__((ext_vector_type(2)));
typedef __bf16 bf16x8 __attribute__((ext_vector_type(8)));
typedef unsigned short ushort_t;

typedef __attribute__((address_space(1))) void gvoid;
typedef __attribute__((address_space(3))) void lvoid;

__device__ inline unsigned short f2bf(float f) {
  unsigned int u = __float_as_uint(f);
  u += 0x7fffu + ((u >> 16) & 1u);
  return (unsigned short)(u >> 16);
}
__device__ inline float bf2f(unsigned short h) {
  return __uint_as_float(((unsigned int)h) << 16);
}

__device__ inline void gload_lds16(const void* g, void* l) {
  // 16B per lane; LDS dest is wave-uniform base + lane*16 (HW rule)
  __builtin_amdgcn_global_load_lds((gvoid*)g, (lvoid*)l, 16, 0, 0);
}

// ---------------------------------------------------------------------------
// Transpose + convert: in f32/bf16 [R][C] -> out bf16 [C][R].  Tile 64x64.
// rmode: 0 identity; 1 gate-interleave row=(n>>4)*32+(n&15); 2 up (+16).
// ---------------------------------------------------------------------------
template <typename TIN>
__global__ __launch_bounds__(256) void k_transpose_bf16(const TIN* __restrict__ in,
                                                        ushort_t* __restrict__ out,
                                                        int R, int C, int rmode) {
  __shared__ float tile[64 * 72];
  int tid = threadIdx.x;
  int r0 = blockIdx.y * 64, c0 = blockIdx.x * 64;
  int rl = tid >> 4;   // 0..15
  int cc = tid & 15;   // 16B col chunk
#pragma unroll
  for (int i = 0; i < 4; ++i) {
    int row = rl + i * 16;
    const TIN* src = in + (size_t)(r0 + row) * C + c0 + cc * 4;
    float v0, v1, v2, v3;
    if constexpr (sizeof(TIN) == 4) {
      f32x4 v = *(const f32x4*)src;
      v0 = v.x; v1 = v.y; v2 = v.z; v3 = v.w;
    } else {
      ushort4 v = *(const ushort4*)src;
      v0 = bf2f(v.x); v1 = bf2f(v.y); v2 = bf2f(v.z); v3 = bf2f(v.w);
    }
    int chunk = cc ^ (row & 15);
    f32x4 t = {v0, v1, v2, v3};
    *(f32x4*)&tile[row * 72 + chunk * 4] = t;
  }
  __syncthreads();
#pragma unroll
  for (int i = 0; i < 4; ++i) {
    int nrow = rl + i * 16;   // output row local = input col
    int k4 = cc * 4;          // output col local base = input row
    ushort4 o;
    {
      int k = k4 + 0;
      o.x = f2bf(tile[k * 72 + (((nrow >> 2) ^ (k & 15)) << 2) + (nrow & 3)]);
      k = k4 + 1;
      o.y = f2bf(tile[k * 72 + (((nrow >> 2) ^ (k & 15)) << 2) + (nrow & 3)]);
      k = k4 + 2;
      o.z = f2bf(tile[k * 72 + (((nrow >> 2) ^ (k & 15)) << 2) + (nrow & 3)]);
      k = k4 + 3;
      o.w = f2bf(tile[k * 72 + (((nrow >> 2) ^ (k & 15)) << 2) + (nrow & 3)]);
    }
    int n = c0 + nrow;
    int orow = n;
    if (rmode == 1) orow = ((n >> 4) << 5) + (n & 15);
    else if (rmode == 2) orow = ((n >> 4) << 5) + 16 + (n & 15);
    *(ushort4*)(out + (size_t)orow * R + r0 + k4) = o;
  }
}

// ---------------------------------------------------------------------------
// RMSNorm over D=2048, one block (256 thr) per row.
// ---------------------------------------------------------------------------
template <int BF16OUT>
__global__ __launch_bounds__(256) void k_rmsnorm(const float* __restrict__ X,
                                                 const float* __restrict__ W,
                                                 void* __restrict__ OUT) {
  int row = blockIdx.x, tid = threadIdx.x;
  const float* xr = X + (size_t)row * DMODEL;
  f32x4 x0 = *(const f32x4*)(xr + tid * 4);
  f32x4 x1 = *(const f32x4*)(xr + 1024 + tid * 4);
  float ss = x0.x * x0.x + x0.y * x0.y + x0.z * x0.z + x0.w * x0.w +
             x1.x * x1.x + x1.y * x1.y + x1.z * x1.z + x1.w * x1.w;
#pragma unroll
  for (int o = 1; o < 64; o <<= 1) ss += __shfl_xor(ss, o, 64);
  __shared__ float red[4];
  int w = tid >> 6;
  if ((tid & 63) == 0) red[w] = ss;
  __syncthreads();
  float tot = red[0] + red[1] + red[2] + red[3];
  float sc = rsqrtf(tot / (float)DMODEL + 1e-6f);
  f32x4 w0 = *(const f32x4*)(W + tid * 4);
  f32x4 w1 = *(const f32x4*)(W + 1024 + tid * 4);
  if constexpr (BF16OUT) {
    ushort_t* o = (ushort_t*)OUT + (size_t)row * DMODEL;
    ushort4 a, b;
    a.x = f2bf(x0.x * sc * w0.x); a.y = f2bf(x0.y * sc * w0.y);
    a.z = f2bf(x0.z * sc * w0.z); a.w = f2bf(x0.w * sc * w0.w);
    b.x = f2bf(x1.x * sc * w1.x); b.y = f2bf(x1.y * sc * w1.y);
    b.z = f2bf(x1.z * sc * w1.z); b.w = f2bf(x1.w * sc * w1.w);
    *(ushort4*)(o + tid * 4) = a;
    *(ushort4*)(o + 1024 + tid * 4) = b;
  } else {
    float* o = (float*)OUT + (size_t)row * DMODEL;
    f32x4 a = {x0.x * sc * w0.x, x0.y * sc * w0.y, x0.z * sc * w0.z, x0.w * sc * w0.w};
    f32x4 b = {x1.x * sc * w1.x, x1.y * sc * w1.y, x1.z * sc * w1.z, x1.w * sc * w1.w};
    *(f32x4*)(o + tid * 4) = a;
    *(f32x4*)(o + 1024 + tid * 4) = b;
  }
}

// ---------------------------------------------------------------------------
// Fused: OUT[row] = RES[row] + sum_z P_bf16[z][row]; optionally
// HB[row] = rmsnorm(OUT[row]) * W  (bf16).  One block (512 thr) per row.
// ---------------------------------------------------------------------------
template <int NZ, int WRITEH>
__global__ __launch_bounds__(512) void k_redln(const ushort_t* __restrict__ P,
                                               const float* __restrict__ RES,
                                               const float* __restrict__ W,
                                               float* __restrict__ OUT,
                                               ushort_t* __restrict__ HB) {
  int row = blockIdx.x, tid = threadIdx.x;
  size_t base = (size_t)row * DMODEL + tid * 4;
  f32x4 v = *(const f32x4*)(RES + base);
#pragma unroll
  for (int z = 0; z < NZ; ++z) {
    ushort4 t = *(const ushort4*)(P + (size_t)z * T_SEQ * DMODEL + base);
    v.x += bf2f(t.x); v.y += bf2f(t.y); v.z += bf2f(t.z); v.w += bf2f(t.w);
  }
  *(f32x4*)(OUT + base) = v;
  if constexpr (WRITEH) {
    float ss = v.x * v.x + v.y * v.y + v.z * v.z + v.w * v.w;
#pragma unroll
    for (int o = 1; o < 64; o <<= 1) ss += __shfl_xor(ss, o, 64);
    __shared__ float red[8];
    if ((tid & 63) == 0) red[tid >> 6] = ss;
    __syncthreads();
    float tot = 0.f;
#pragma unroll
    for (int i = 0; i < 8; ++i) tot += red[i];
    float sc = rsqrtf(tot / (float)DMODEL + 1e-6f);
    f32x4 wv = *(const f32x4*)(W + tid * 4);
    ushort4 h;
    h.x = f2bf(v.x * sc * wv.x); h.y = f2bf(v.y * sc * wv.y);
    h.z = f2bf(v.z * sc * wv.z); h.w = f2bf(v.w * sc * wv.w);
    *(ushort4*)(HB + base) = h;
  }
}

// ---------------------------------------------------------------------------
// 256x256 GEMM, pipelined core: 8 waves 4Mx2N, BK=64, LDS 128KB dbuf.
// Per K-tile: ONE barrier + ONE vmcnt(0) (stages issued a full tile earlier).
// Within-wave pipeline: quadrant q issues next quadrant's 4 ds_read_b128,
// waits lgkmcnt(4) (counted), sched_barrier, MFMAs current quadrant from the
// other register set.  Stage writes go to the LDS buffer NOT in use, so no
// within-tile barriers are needed; tile-end barrier publishes both
// "reads of buf d done" and "stages into buf d^1 complete".
// Square-chunk XCD swizzle.  EPI: 3 store bf16, 5 fused SiLU-GLU.
// ---------------------------------------------------------------------------
#define EPI_STOREB 3
#define EPI_GLU 5

#define LOADB(dst, bs, rbase)                                                  \
  {                                                                            \
    _Pragma("unroll") for (int ks = 0; ks < 2; ++ks)                           \
        _Pragma("unroll") for (int ni = 0; ni < 2; ++ni)                       \
            dst[ks][ni] = *(const bf16x8*)((bs) +                              \
                (((rbase) + ni * 16 + lr) << 6) +                              \
                ((((ks << 2) + lg) ^ (lr & 7)) << 3));                         \
  }

#define MFMA_Q(q, B)                                                           \
  {                                                                            \
    _Pragma("unroll") for (int ks = 0; ks < 2; ++ks)                           \
        _Pragma("unroll") for (int mi = 0; mi < 4; ++mi)                       \
            _Pragma("unroll") for (int ni = 0; ni < 2; ++ni)                   \
                acc[mi][(q) * 2 + ni] =                                        \
                    __builtin_amdgcn_mfma_f32_16x16x32_bf16(                   \
                        af[ks][mi], B[ks][ni], acc[mi][(q) * 2 + ni], 0, 0, 0); \
  }

template <int LAST>
__device__ __forceinline__ void g256_iter(
    const ushort_t* __restrict__ as, const ushort_t* __restrict__ bsA,
    const ushort_t* __restrict__ bsB, ushort_t* __restrict__ nA,
    ushort_t* __restrict__ nB, const ushort_t* __restrict__ an,
    const ushort_t* __restrict__ bn, size_t rs, int slds, int lr, int lg,
    f32x4 (&acc)[4][8]) {
  bf16x8 af[2][4], b0[2][2], b1[2][2];
  // tile head: A frags (8 ds) + B quadrant0 (4 ds); issue all 8 next stages.
#pragma unroll
  for (int ks = 0; ks < 2; ++ks)
#pragma unroll
    for (int mi = 0; mi < 4; ++mi)
      af[ks][mi] = *(const bf16x8*)(as + ((mi * 16 + lr) << 6) +
                                    ((((ks << 2) + lg) ^ (lr & 7)) << 3));
  LOADB(b0, bsA, 0);
  if constexpr (!LAST) {
    gload_lds16(an, nA + slds);
    gload_lds16(an + rs, nA + 4096 + slds);
    gload_lds16(an + 2 * rs, nA + 8192 + slds);
    gload_lds16(an + 3 * rs, nA + 12288 + slds);
    gload_lds16(bn, nB + slds);
    gload_lds16(bn + rs, nB + 4096 + slds);
    gload_lds16(bn + 2 * rs, nB + 8192 + slds);
    gload_lds16(bn + 3 * rs, nB + 12288 + slds);
  }
  // q0: issue quadrant1 reads, wait for af+b0 (12 oldest of 16), MFMA b0
  LOADB(b1, bsA, 32);
  asm volatile("s_waitcnt lgkmcnt(4)" ::: "memory");
  __builtin_amdgcn_sched_barrier(0);
  __builtin_amdgcn_s_setprio(1);
  MFMA_Q(0, b0);
  __builtin_amdgcn_s_setprio(0);
  // q1: issue quadrant2, wait b1, MFMA b1
  LOADB(b0, bsB, 0);
  asm volatile("s_waitcnt lgkmcnt(4)" ::: "memory");
  __builtin_amdgcn_sched_barrier(0);
  __builtin_amdgcn_s_setprio(1);
  MFMA_Q(1, b1);
  __builtin_amdgcn_s_setprio(0);
  // q2: issue quadrant3, wait b0, MFMA b0
  LOADB(b1, bsB, 32);
  asm volatile("s_waitcnt lgkmcnt(4)" ::: "memory");
  __builtin_amdgcn_sched_barrier(0);
  __builtin_amdgcn_s_setprio(1);
  MFMA_Q(2, b0);
  __builtin_amdgcn_s_setprio(0);
  // q3: wait b1, MFMA b1
  asm volatile("s_waitcnt lgkmcnt(0)" ::: "memory");
  __builtin_amdgcn_sched_barrier(0);
  __builtin_amdgcn_s_setprio(1);
  MFMA_Q(3, b1);
  __builtin_amdgcn_s_setprio(0);
  if constexpr (!LAST) {
    // stages issued at tile head have had a full tile of compute in flight
    asm volatile("s_waitcnt vmcnt(0)" ::: "memory");
    __builtin_amdgcn_s_barrier();
  }
}

template <int EPI>
__global__ __launch_bounds__(512, 2) void k_gemm256(
    const ushort_t* __restrict__ A, const ushort_t* __restrict__ BT,
    ushort_t* __restrict__ CB, int N, int Kstride, int Kc, size_t zoff) {
  __shared__ ushort_t lds[65536];  // 128 KiB
  const int tid = threadIdx.x;
  const int l = tid & 63, wid = tid >> 6;
  const int wm = wid >> 1, wn = wid & 1;
  const int lr = l & 15, lg = l >> 4;
  // Square-chunk XCD swizzle: XCD x (= bid%8) owns a 4m x cn tile chunk.
  const int gx = gridDim.x;
  const int nwg = gx * gridDim.y;
  const int bid = blockIdx.x + gx * blockIdx.y;
  const int chunk = nwg >> 3;
  const int x = bid & 7;
  const int local = bid >> 3;
  const int cn = chunk >> 2;           // cm = 4
  const int ncx = gx / cn;
  const int m0 = ((x / ncx) * 4 + local / cn) * 256;
  const int n0 = ((x % ncx) * cn + local % cn) * 256;
  const int z = blockIdx.z;
  const int NT = Kc >> 6;

  A += (size_t)z * Kc;
  BT += (size_t)z * Kc;
  CB += (size_t)z * zoff;

  const int srow = tid >> 3;                    // 0..63 row within a slot
  const int scs = (tid & 7) ^ (srow & 7);       // pre-swizzled source chunk
  const size_t sgoff = (size_t)srow * Kstride + scs * 8;
  const int slds = wid * 512;                   // wave-uniform ushort offset

  const ushort_t* ga = A + (size_t)m0 * Kstride + sgoff;
  const ushort_t* gb = BT + (size_t)n0 * Kstride + sgoff;
  const size_t rs = (size_t)64 * Kstride;       // 64-row stride (elements)

  f32x4 acc[4][8] = {};

  ushort_t* Ab0 = lds;
  ushort_t* Bb0 = lds + 16384;
  ushort_t* Ab1 = lds + 32768;
  ushort_t* Bb1 = lds + 49152;

  // prologue: tile0 -> dbuf0
  gload_lds16(ga, Ab0 + slds);
  gload_lds16(ga + rs, Ab0 + 4096 + slds);
  gload_lds16(ga + 2 * rs, Ab0 + 8192 + slds);
  gload_lds16(ga + 3 * rs, Ab0 + 12288 + slds);
  gload_lds16(gb, Bb0 + slds);
  gload_lds16(gb + rs, Bb0 + 4096 + slds);
  gload_lds16(gb + 2 * rs, Bb0 + 8192 + slds);
  gload_lds16(gb + 3 * rs, Bb0 + 12288 + slds);
  asm volatile("s_waitcnt vmcnt(0)" ::: "memory");
  __builtin_amdgcn_s_barrier();

  for (int kt = 0; kt < NT - 1; ++kt) {
    const int d = kt & 1;
    const ushort_t* as = (d ? Ab1 : Ab0) + wm * 4096;
    const ushort_t* bsA = (d ? Bb1 : Bb0) + (wn * 2) * 4096;
    ushort_t* nA = d ? Ab0 : Ab1;
    ushort_t* nB = d ? Bb0 : Bb1;
    g256_iter<0>(as, bsA, bsA + 4096, nA, nB, ga + (size_t)(kt + 1) * 64,
                 gb + (size_t)(kt + 1) * 64, rs, slds, lr, lg, acc);
  }
  {
    const int d = (NT - 1) & 1;
    const ushort_t* as = (d ? Ab1 : Ab0) + wm * 4096;
    const ushort_t* bsA = (d ? Bb1 : Bb0) + (wn * 2) * 4096;
    g256_iter<1>(as, bsA, bsA + 4096, nullptr, nullptr, nullptr, nullptr, rs,
                 slds, lr, lg, acc);
  }

  // epilogue
  if constexpr (EPI == EPI_GLU) {
    // Interleaved gate/up: even ci = gate, odd ci = up (same lane, same col).
#pragma unroll
    for (int mi = 0; mi < 4; ++mi)
#pragma unroll
      for (int ci = 0; ci < 8; ci += 2)
#pragma unroll
        for (int rr = 0; rr < 4; ++rr) {
          int m = m0 + wm * 64 + mi * 16 + lg * 4 + rr;
          int nblk = n0 + wn * 128 + ci * 16;
          int col = ((nblk >> 5) << 4) + lr;
          float gv = acc[mi][ci][rr];
          float uv = acc[mi][ci + 1][rr];
          float s = gv / (1.f + __expf(-gv));
          CB[(size_t)m * 8192 + col] = f2bf(s * uv);
        }
  } else {
#pragma unroll
    for (int mi = 0; mi < 4; ++mi)
#pragma unroll
      for (int ci = 0; ci < 8; ++ci)
#pragma unroll
        for (int rr = 0; rr < 4; ++rr) {
          int m = m0 + wm * 64 + mi * 16 + lg * 4 + rr;
          int n = n0 + wn * 128 + ci * 16 + lr;
          CB[(size_t)m * N + n] = f2bf(acc[mi][ci][rr]);
        }
  }
}

// ---------------------------------------------------------------------------
// Post-QKV: sum 2 bf16 split-K partials + per-head RMSNorm (q,k) + RoPE.
// ---------------------------------------------------------------------------
__global__ __launch_bounds__(256) void k_qkv_post(const ushort_t* __restrict__ Q0,
                                                  const ushort_t* __restrict__ Q1,
                                                  const float* __restrict__ QNW,
                                                  const float* __restrict__ KNW,
                                                  const int* __restrict__ POS,
                                                  ushort_t* __restrict__ Qb,
                                                  ushort_t* __restrict__ Kb,
                                                  ushort_t* __restrict__ Vb) {
  int t = blockIdx.x;
  int tid = threadIdx.x;
  int w = tid >> 6, l = tid & 63;
  float pos = (float)POS[t];
  const ushort_t* base0 = Q0 + (size_t)t * 4096;
  const ushort_t* base1 = Q1 + (size_t)t * 4096;
  int i0 = 2 * (l & 31);
  const float K2 = 19.931568569324174f / 64.f;  // log2(1e6)/64
  float ang0 = pos * exp2f(-(float)i0 * K2);
  float ang1 = pos * exp2f(-(float)(i0 + 1) * K2);
  float cs0 = cosf(ang0), sn0 = sinf(ang0);
  float cs1 = cosf(ang1), sn1 = sinf(ang1);
#pragma unroll
  for (int si = 0; si < 8; ++si) {
    int slot = w + si * 4;
    ushort2 xa = *(const ushort2*)(base0 + slot * 128 + l * 2);
    ushort2 xb = *(const ushort2*)(base1 + slot * 128 + l * 2);
    float v0 = bf2f(xa.x) + bf2f(xb.x), v1 = bf2f(xa.y) + bf2f(xb.y);
    float ss = v0 * v0 + v1 * v1;
#pragma unroll
    for (int o = 1; o < 64; o <<= 1) ss += __shfl_xor(ss, o, 64);
    if (slot < 24) {
      float sc = rsqrtf(ss / 128.f + 1e-6f);
      const float* wn = (slot < 16) ? QNW : KNW;
      f32x2 wv = *(const f32x2*)(wn + l * 2);
      v0 = v0 * sc * wv.x;
      v1 = v1 * sc * wv.y;
      float p0 = __shfl_xor(v0, 32, 64);
      float p1 = __shfl_xor(v1, 32, 64);
      float r0 = (l < 32) ? -p0 : p0;
      float r1 = (l < 32) ? -p1 : p1;
      v0 = v0 * cs0 + r0 * sn0;
      v1 = v1 * cs1 + r1 * sn1;
    }
    ushort2 uv;
    uv.x = f2bf(v0);
    uv.y = f2bf(v1);
    ushort_t* dst;
    if (slot < 16)
      dst = Qb + (size_t)t * 2048 + slot * 128 + l * 2;
    else if (slot < 24)
      dst = Kb + (size_t)t * 1024 + (slot - 16) * 128 + l * 2;
    else
      dst = Vb + (size_t)t * 1024 + (slot - 24) * 128 + l * 2;
    *(ushort2*)dst = uv;
  }
}

// ---------------------------------------------------------------------------
// Flash attention, ragged causal mask.  1 wave per (16 q rows, KV head);
// both q-heads of the GQA group computed in-wave (shared K/V fragments).
// No __syncthreads: single-wave block, P-LDS roundtrip ordered by lgkmcnt.
// ---------------------------------------------------------------------------
__global__ __launch_bounds__(64) void k_flash(const ushort_t* __restrict__ Qb,
                                              const ushort_t* __restrict__ Kb,
                                              const ushort_t* __restrict__ VT,
                                              const int* __restrict__ SEG,
                                              ushort_t* __restrict__ Ob) {
  __shared__ ushort_t Pl[2][16 * 40];
  int l = threadIdx.x;
  int qt = blockIdx.x, kvh = blockIdx.y;
  int q0 = qt * 16;
  int lr = l & 15, lg = l >> 4;
  int h0 = kvh * 2;
  bf16x8 qf0[4], qf1[4];
  {
    const bf16x8* qv = (const bf16x8*)(Qb + (size_t)(q0 + lr) * 2048 + h0 * 128);
#pragma unroll
    for (int kk = 0; kk < 4; ++kk) {
      qf0[kk] = qv[kk * 4 + lg];
      qf1[kk] = qv[16 + kk * 4 + lg];
    }
  }
  int segq[4];
#pragma unroll
  for (int r = 0; r < 4; ++r) segq[r] = SEG[q0 + lg * 4 + r];
  int target = SEG[q0];
  int lo = 0, hi = q0;
  while (lo < hi) {
    int mid = (lo + hi) >> 1;
    if (SEG[mid] < target) lo = mid + 1; else hi = mid;
  }
  int s_start = lo & ~31;
  float mr[2][4], lrun[2][4];
  f32x4 acc[2][8] = {};
#pragma unroll
  for (int h = 0; h < 2; ++h)
#pragma unroll
    for (int r = 0; r < 4; ++r) { mr[h][r] = -1e30f; lrun[h][r] = 0.f; }
  const float scale = 0.08838834764831845f;  // 1/sqrt(128)
  for (int s0 = s_start; s0 < q0 + 16; s0 += 32) {
    int sa = s0 + lr, sb = s0 + 16 + lr;
    int sac = min(sa, T_SEQ - 1), sbc = min(sb, T_SEQ - 1);
    // V fragments issued early; consumed only after the P roundtrip.
    bf16x8 vfr[8];
    int sbase = min(s0 + lg * 8, T_SEQ - 8);
#pragma unroll
    for (int c = 0; c < 8; ++c)
      vfr[c] = *(const bf16x8*)(VT + (size_t)(kvh * 128 + c * 16 + lr) * T_SEQ + sbase);
    f32x4 SA0 = {}, SB0 = {}, SA1 = {}, SB1 = {};
    const bf16x8* ka = (const bf16x8*)(Kb + (size_t)sac * 1024 + kvh * 128);
    const bf16x8* kb_ = (const bf16x8*)(Kb + (size_t)sbc * 1024 + kvh * 128);
#pragma unroll
    for (int kk = 0; kk < 4; ++kk) {
      bf16x8 kaf = ka[kk * 4 + lg];
      bf16x8 kbf = kb_[kk * 4 + lg];
      SA0 = __builtin_amdgcn_mfma_f32_16x16x32_bf16(qf0[kk], kaf, SA0, 0, 0, 0);
      SB0 = __builtin_amdgcn_mfma_f32_16x16x32_bf16(qf0[kk], kbf, SB0, 0, 0, 0);
      SA1 = __builtin_amdgcn_mfma_f32_16x16x32_bf16(qf1[kk], kaf, SA1, 0, 0, 0);
      SB1 = __builtin_amdgcn_mfma_f32_16x16x32_bf16(qf1[kk], kbf, SB1, 0, 0, 0);
    }
    int sga = SEG[sac], sgb = SEG[sbc];
    bool mAv[4], mBv[4];
#pragma unroll
    for (int r = 0; r < 4; ++r) {
      int qrow = q0 + lg * 4 + r;
      mAv[r] = (sa <= qrow) && (sga == segq[r]);
      mBv[r] = (sb <= qrow) && (sgb == segq[r]);
    }
#pragma unroll
    for (int h = 0; h < 2; ++h) {
#pragma unroll
      for (int r = 0; r < 4; ++r) {
        float sva = (h ? SA1[r] : SA0[r]);
        float svb = (h ? SB1[r] : SB0[r]);
        float xa = mAv[r] ? sva * scale : -1e30f;
        float xb = mBv[r] ? svb * scale : -1e30f;
        float mx = fmaxf(xa, xb);
#pragma unroll
        for (int o = 1; o < 16; o <<= 1) mx = fmaxf(mx, __shfl_xor(mx, o, 64));
        float nm = fmaxf(mr[h][r], mx);
        float ea = __expf(xa - nm), eb = __expf(xb - nm);
        float rsum = ea + eb;
#pragma unroll
        for (int o = 1; o < 16; o <<= 1) rsum += __shfl_xor(rsum, o, 64);
        float al = __expf(mr[h][r] - nm);
        lrun[h][r] = lrun[h][r] * al + rsum;
        mr[h][r] = nm;
#pragma unroll
        for (int c = 0; c < 8; ++c) acc[h][c][r] *= al;
        Pl[h][(lg * 4 + r) * 40 + lr] = f2bf(ea);
        Pl[h][(lg * 4 + r) * 40 + 16 + lr] = f2bf(eb);
      }
    }
    // single-wave block: LDS ordering only (keeps global loads in flight)
    asm volatile("s_waitcnt lgkmcnt(0)" ::: "memory");
    bf16x8 pa0 = *(const bf16x8*)&Pl[0][lr * 40 + lg * 8];
    bf16x8 pa1 = *(const bf16x8*)&Pl[1][lr * 40 + lg * 8];
#pragma unroll
    for (int c = 0; c < 8; ++c) {
      acc[0][c] = __builtin_amdgcn_mfma_f32_16x16x32_bf16(pa0, vfr[c], acc[0][c], 0, 0, 0);
      acc[1][c] = __builtin_amdgcn_mfma_f32_16x16x32_bf16(pa1, vfr[c], acc[1][c], 0, 0, 0);
    }
  }
#pragma unroll
  for (int h = 0; h < 2; ++h)
#pragma unroll
    for (int c = 0; c < 8; ++c)
#pragma unroll
      for (int r = 0; r < 4; ++r) {
        float ov = acc[h][c][r] / lrun[h][r];
        Ob[(size_t)(q0 + lg * 4 + r) * 2048 + (h0 + h) * 128 + c * 16 + lr] = f2bf(ov);
      }
}

// ---------------------------------------------------------------------------
extern "C" void kernel_launch(void* const* d_in, const int* in_sizes, int n_in,
                              void* d_out, int out_size, void* d_ws, size_t ws_size,
                              hipStream_t stream) {
  const float* hidden = (const float*)d_in[0];
  const float* ln1 = (const float*)d_in[1];
  const float* ln2 = (const float*)d_in[2];
  const float* wq = (const float*)d_in[3];
  const float* wk = (const float*)d_in[4];
  const float* wv = (const float*)d_in[5];
  const float* wo = (const float*)d_in[6];
  const float* qnw = (const float*)d_in[7];
  const float* knw = (const float*)d_in[8];
  const float* wg = (const float*)d_in[9];
  const float* wu = (const float*)d_in[10];
  const float* wd = (const float*)d_in[11];
  const float* fnw = (const float*)d_in[12];
  const int* seg = (const int*)d_in[13];
  const int* pos = (const int*)d_in[14];
  float* out = (float*)d_out;

  char* ws = (char*)d_ws;
  size_t off = 0;
  auto alloc = [&](size_t bytes) {
    char* p = ws + off;
    off += (bytes + 255) & ~(size_t)255;
    return p;
  };
  ushort_t* wT = (ushort_t*)alloc((size_t)2 * DFF * DMODEL * 2);   // 67MB (fused gate/up)
  ushort_t* hbuf = (ushort_t*)alloc((size_t)T_SEQ * DMODEL * 2);
  ushort_t* qb = (ushort_t*)alloc((size_t)T_SEQ * 2048 * 2);
  ushort_t* kb = (ushort_t*)alloc((size_t)T_SEQ * 1024 * 2);
  ushort_t* vb = (ushort_t*)alloc((size_t)T_SEQ * 1024 * 2);
  ushort_t* vT = (ushort_t*)alloc((size_t)T_SEQ * 1024 * 2);
  ushort_t* ob = (ushort_t*)alloc((size_t)T_SEQ * 2048 * 2);
  ushort_t* qkvp = (ushort_t*)alloc((size_t)2 * T_SEQ * 4096 * 2); // bf16 partials
  ushort_t* pbuf = (ushort_t*)alloc((size_t)4 * T_SEQ * DMODEL * 2);
  ushort_t* mbuf = (ushort_t*)alloc((size_t)T_SEQ * DFF * 2);
  (void)ws_size; (void)in_sizes; (void)n_in; (void)out_size;

  dim3 b256(256), b64(64), b512(512);
  // layer-0 input norm
  k_rmsnorm<1><<<T_SEQ, b256, 0, stream>>>(hidden, ln1, hbuf);

  for (int lyr = 0; lyr < 2; ++lyr) {
    const float* xsrc = (lyr == 0) ? hidden : out;

    const float* wql = wq + (size_t)lyr * DMODEL * 2048;
    const float* wkl = wk + (size_t)lyr * DMODEL * 1024;
    const float* wvl = wv + (size_t)lyr * DMODEL * 1024;
    k_transpose_bf16<float><<<dim3(32, 32), b256, 0, stream>>>(wql, wT, 2048, 2048, 0);
    k_transpose_bf16<float><<<dim3(16, 32), b256, 0, stream>>>(wkl, wT + (size_t)2048 * 2048, 2048, 1024, 0);
    k_transpose_bf16<float><<<dim3(16, 32), b256, 0, stream>>>(wvl, wT + (size_t)3072 * 2048, 2048, 1024, 0);
    // QKV split-K=2 (Kc=1024): bf16 partials -> qkvp[z * 2048*4096]
    k_gemm256<EPI_STOREB><<<dim3(16, 8, 2), b512, 0, stream>>>(
        hbuf, wT, qkvp, 4096, 2048, 1024, (size_t)2048 * 4096);
    k_qkv_post<<<T_SEQ, b256, 0, stream>>>(qkvp, qkvp + (size_t)2048 * 4096,
                                           qnw + (size_t)lyr * 128, knw + (size_t)lyr * 128,
                                           pos, qb, kb, vb);
    k_transpose_bf16<ushort_t><<<dim3(16, 32), b256, 0, stream>>>(vb, vT, 2048, 1024, 0);
    k_flash<<<dim3(T_SEQ / 16, NKV), b64, 0, stream>>>(qb, kb, vT, seg, ob);

    const float* wol = wo + (size_t)lyr * 2048 * DMODEL;
    k_transpose_bf16<float><<<dim3(32, 32), b256, 0, stream>>>(wol, wT, 2048, 2048, 0);
    // WO split-K=4 (Kc=512): bf16 partials, then fused residual+reduce+ln2
    k_gemm256<EPI_STOREB><<<dim3(8, 8, 4), b512, 0, stream>>>(
        ob, wT, pbuf, 2048, 2048, 512, (size_t)2048 * 2048);
    k_redln<4, 1><<<T_SEQ, b512, 0, stream>>>(pbuf, xsrc,
                                              ln2 + (size_t)lyr * DMODEL, out, hbuf);

    const float* wgl = wg + (size_t)lyr * DMODEL * DFF;
    const float* wul = wu + (size_t)lyr * DMODEL * DFF;
    const float* wdl = wd + (size_t)lyr * DFF * DMODEL;
    // Fused gate+up: interleaved transpose into wT [16384][2048], one GEMM
    // with in-register SiLU-GLU epilogue -> mbuf bf16 [2048][8192].
    k_transpose_bf16<float><<<dim3(128, 32), b256, 0, stream>>>(wgl, wT, 2048, 8192, 1);
    k_transpose_bf16<float><<<dim3(128, 32), b256, 0, stream>>>(wul, wT, 2048, 8192, 2);
    k_gemm256<EPI_GLU><<<dim3(64, 8, 1), b512, 0, stream>>>(
        hbuf, wT, mbuf, 16384, 2048, 2048, 0);
    k_transpose_bf16<float><<<dim3(32, 128), b256, 0, stream>>>(wdl, wT, 8192, 2048, 0);
    // WD split-K=4 (Kc=2048): bf16 partials, fused residual+reduce(+next ln1)
    k_gemm256<EPI_STOREB><<<dim3(8, 8, 4), b512, 0, stream>>>(
        mbuf, wT, pbuf, 2048, 8192, 2048, (size_t)2048 * 2048);
    if (lyr == 0) {
      k_redln<4, 1><<<T_SEQ, b512, 0, stream>>>(pbuf, out, ln1 + DMODEL, out, hbuf);
    } else {
      k_redln<4, 0><<<T_SEQ, b512, 0, stream>>>(pbuf, out, nullptr, out, nullptr);
    }
  }
  k_rmsnorm<0><<<T_SEQ, b256, 0, stream>>>(out, fnw, out);
}